// Round 11
// baseline (13578.276 us; speedup 1.0000x reference)
//
#include <hip/hip_runtime.h>

// RNN: h_t = tanh(E[x_t] + h_{t-1} @ Whh + bh), T=1024, N=64, H=1024.
// y = softmax(z @ Wout + bout). Output: y (64*1024*256 f32) then h_last (64*1024 f32).
//
// Double-FP16 recurrence (hi + 2^-11*lo of h and Whh) -> fp32-equivalent
// per-step precision (R3..R8: passed, absmax 9.8e-4).
//
// R11 = R10's XCD partition + R8's PROVEN coherence protocol.
// R10 (sc0-only, L2-local exchange) failed absmax 0.198: clean-stale lines in
// consumer XCDs' L2 across chunk/kernel boundaries (kernel-end release flushes
// producer dirty lines, doesn't invalidate other XCDs' clean copies) -> poll
// guard expired on stale-zero flag lines -> stale h -> chaotic amplification.
// Reverted protocol: h stores sc0 sc1 (to coherence point) + vmcnt(0); flag =
// relaxed agent atomic; consumer relaxed poll (no guard) + ONE agent acquire
// fence per step; A-loads plain cached, all 32 issued in ONE asm batch with a
// single vmcnt drain (32-deep pipeline, ~1 L3 round trip).
// Partition kept from R10: 8 seqs per XCD (XCC_ID + claim counter), 32 worker
// WGs per XCD, each owns 8 seqs x 32 cols; Whh B-slice hi/lo in 128 KB LDS;
// per-WG h read = 32 KB/step (vs 256 KB in R5-R8), shared via L2 by the
// XCD's 32 WGs after the fence.

typedef _Float16 f16x8 __attribute__((ext_vector_type(8)));
typedef float    f32x4 __attribute__((ext_vector_type(4)));

#define NSEQ  64
#define TSEQ  1024
#define HDIM  1024
#define VOCABSZ 256
#define ODIM  256
#define LOSCALE 2048.0f
#define LOINV  (1.0f/2048.0f)

// hbuf layout: [buf(2)][plane(2: hi,lo)][NSEQ][HDIM] fp16
#define HPLANE (NSEQ * HDIM)
#define HBUFSZ (2 * HPLANE)

// ---------------------------------------------------------------- init / prep
__global__ __launch_bounds__(256) void rnn_init(
    const float* __restrict__ Whh, const float* __restrict__ Wout,
    const float* __restrict__ E,   const float* __restrict__ bh,
    _Float16* __restrict__ whhT_hi, _Float16* __restrict__ whhT_lo,
    _Float16* __restrict__ woutT,  float* __restrict__ e2,
    _Float16* __restrict__ hbuf, unsigned* __restrict__ flags,
    unsigned* __restrict__ claims)
{
    int i = blockIdx.x * 256 + threadIdx.x;
    int stride = gridDim.x * 256;
    for (int idx = i; idx < HDIM * HDIM; idx += stride) {
        int j = idx >> 10, k = idx & 1023;
        float w = Whh[k * HDIM + j];
        _Float16 hi = (_Float16)w;
        whhT_hi[idx] = hi;
        whhT_lo[idx] = (_Float16)((w - (float)hi) * LOSCALE);
    }
    for (int idx = i; idx < ODIM * HDIM; idx += stride) {
        int o = idx >> 10, k = idx & 1023;
        woutT[idx] = (_Float16)Wout[k * ODIM + o];
    }
    for (int idx = i; idx < VOCABSZ * HDIM; idx += stride) {
        int j = idx & 1023;
        e2[idx] = E[idx] + bh[j];
    }
    for (int idx = i; idx < 2 * HBUFSZ; idx += stride) hbuf[idx] = (_Float16)0.f;
    for (int idx = i; idx < TSEQ * 256; idx += stride) flags[idx] = 0u;
    for (int idx = i; idx < 64 * 8; idx += stride) claims[idx] = 0u;
}

// ---------------------------------------------------------------- recurrence
// 32 plain cached loads (16B each) issued back-to-back, ONE vmcnt(0) drain.
// Early-clobber outputs (written while the 4 address pairs are still live).
#define LOADA32(AH0, AL0, AH1, AL1, B0, B1, B2, B3)                          \
    asm volatile(                                                            \
        "global_load_dwordx4 %[a0], %[q0], off\n\t"                          \
        "global_load_dwordx4 %[a1], %[q0], off offset:64\n\t"                \
        "global_load_dwordx4 %[a2], %[q0], off offset:128\n\t"               \
        "global_load_dwordx4 %[a3], %[q0], off offset:192\n\t"               \
        "global_load_dwordx4 %[a4], %[q0], off offset:256\n\t"               \
        "global_load_dwordx4 %[a5], %[q0], off offset:320\n\t"               \
        "global_load_dwordx4 %[a6], %[q0], off offset:384\n\t"               \
        "global_load_dwordx4 %[a7], %[q0], off offset:448\n\t"               \
        "global_load_dwordx4 %[b0], %[q1], off\n\t"                          \
        "global_load_dwordx4 %[b1], %[q1], off offset:64\n\t"                \
        "global_load_dwordx4 %[b2], %[q1], off offset:128\n\t"               \
        "global_load_dwordx4 %[b3], %[q1], off offset:192\n\t"               \
        "global_load_dwordx4 %[b4], %[q1], off offset:256\n\t"               \
        "global_load_dwordx4 %[b5], %[q1], off offset:320\n\t"               \
        "global_load_dwordx4 %[b6], %[q1], off offset:384\n\t"               \
        "global_load_dwordx4 %[b7], %[q1], off offset:448\n\t"               \
        "global_load_dwordx4 %[c0], %[q2], off\n\t"                          \
        "global_load_dwordx4 %[c1], %[q2], off offset:64\n\t"                \
        "global_load_dwordx4 %[c2], %[q2], off offset:128\n\t"               \
        "global_load_dwordx4 %[c3], %[q2], off offset:192\n\t"               \
        "global_load_dwordx4 %[c4], %[q2], off offset:256\n\t"               \
        "global_load_dwordx4 %[c5], %[q2], off offset:320\n\t"               \
        "global_load_dwordx4 %[c6], %[q2], off offset:384\n\t"               \
        "global_load_dwordx4 %[c7], %[q2], off offset:448\n\t"               \
        "global_load_dwordx4 %[d0], %[q3], off\n\t"                          \
        "global_load_dwordx4 %[d1], %[q3], off offset:64\n\t"                \
        "global_load_dwordx4 %[d2], %[q3], off offset:128\n\t"               \
        "global_load_dwordx4 %[d3], %[q3], off offset:192\n\t"               \
        "global_load_dwordx4 %[d4], %[q3], off offset:256\n\t"               \
        "global_load_dwordx4 %[d5], %[q3], off offset:320\n\t"               \
        "global_load_dwordx4 %[d6], %[q3], off offset:384\n\t"               \
        "global_load_dwordx4 %[d7], %[q3], off offset:448\n\t"               \
        "s_waitcnt vmcnt(0)"                                                 \
        : [a0]"=&v"(AH0[0]), [a1]"=&v"(AH0[1]), [a2]"=&v"(AH0[2]),           \
          [a3]"=&v"(AH0[3]), [a4]"=&v"(AH0[4]), [a5]"=&v"(AH0[5]),           \
          [a6]"=&v"(AH0[6]), [a7]"=&v"(AH0[7]),                              \
          [b0]"=&v"(AL0[0]), [b1]"=&v"(AL0[1]), [b2]"=&v"(AL0[2]),           \
          [b3]"=&v"(AL0[3]), [b4]"=&v"(AL0[4]), [b5]"=&v"(AL0[5]),           \
          [b6]"=&v"(AL0[6]), [b7]"=&v"(AL0[7]),                              \
          [c0]"=&v"(AH1[0]), [c1]"=&v"(AH1[1]), [c2]"=&v"(AH1[2]),           \
          [c3]"=&v"(AH1[3]), [c4]"=&v"(AH1[4]), [c5]"=&v"(AH1[5]),           \
          [c6]"=&v"(AH1[6]), [c7]"=&v"(AH1[7]),                              \
          [d0]"=&v"(AL1[0]), [d1]"=&v"(AL1[1]), [d2]"=&v"(AL1[2]),           \
          [d3]"=&v"(AL1[3]), [d4]"=&v"(AL1[4]), [d5]"=&v"(AL1[5]),           \
          [d6]"=&v"(AL1[6]), [d7]"=&v"(AL1[7])                               \
        : [q0]"v"(B0), [q1]"v"(B1), [q2]"v"(B2), [q3]"v"(B3) : "memory")

__global__ __launch_bounds__(256, 1) void rnn_steps(
    const int*   __restrict__ x,          // [NSEQ][TSEQ]
    const float* __restrict__ e2,         // [VOCAB][HDIM]  (E + bh)
    const _Float16* __restrict__ whhT_hi, // [HDIM][HDIM] j-major
    const _Float16* __restrict__ whhT_lo,
    _Float16* __restrict__ hbuf,
    unsigned* __restrict__ flags,         // [TSEQ][8 xcd][32 slot]
    unsigned* __restrict__ claims,        // [8] for this chunk
    _Float16* __restrict__ z,             // chunk: [tc][NSEQ*HDIM]
    float* __restrict__ hlast_out,        // [NSEQ*HDIM]
    int t0, int t1)
{
    const int tid  = threadIdx.x;
    const int lane = tid & 63;
    const int w    = tid >> 6;         // wave 0..3
    const int lq   = lane >> 4;        // k sub-chunk 0..3

    __shared__ _Float16 bls[2][32][2][64][8];  // 128 KB Whh^T frags hi/lo
    __shared__ f32x4    red[4][64];            //   4 KB wave partials
    __shared__ int      slot_s;
    __shared__ unsigned xcd_s;

    // ---- claim a worker slot on this physical XCD
    if (tid == 0) {
        unsigned xcd;
        asm volatile("s_getreg_b32 %0, hwreg(HW_REG_XCC_ID)" : "=s"(xcd));
        xcd &= 7;
        xcd_s  = xcd;
        slot_s = (int)atomicAdd(&claims[xcd], 1u);
    }
    __syncthreads();
    const int slot = slot_s;
    if (slot >= 32) return;            // surplus block
    const unsigned xcd = xcd_s;
    const int gbase = (int)xcd * 8;    // this XCD's 8 sequences
    const int j0c   = slot * 32;       // this WG's 32 columns

    // ---- one-time: stage B fragments (32 cols, hi+lo) into LDS
    for (int idx = tid; idx < 8192; idx += 256) {
        int l   = idx & 63;
        int ct_ = (idx >> 6) & 1;
        int m   = (idx >> 7) & 31;
        int pl_ = idx >> 12;
        int col = j0c + ct_ * 16 + (l & 15);
        int k   = m * 32 + (l >> 4) * 8;
        const _Float16* s = (pl_ ? whhT_lo : whhT_hi) + (size_t)col * HDIM + k;
        *(f16x8*)&bls[pl_][m][ct_][l][0] = *(const f16x8*)s;
    }
    __syncthreads();

    const int ct = w & 1, p = w >> 1;  // col-tile, k-half of this wave
    const int rowA = lane & 7;

    // epilogue role: one output value per thread
    const int erow = tid >> 5;         // 0..7
    const int ecol = tid & 31;         // 0..31
    const int gn   = gbase + erow;
    const int jcol = j0c + ecol;
    const int ctE  = ecol >> 4;
    const int laneE= ((erow >> 2) << 4) | (ecol & 15);
    const int rE   = erow & 3;

    int   tokv = x[(size_t)gn * TSEQ + t0];
    float ev   = e2[(size_t)tokv * HDIM + jcol];

    for (int t = t0; t < t1; ++t) {
        // prefetch next step's token + E value (read-only, fence-safe)
        int tn = (t + 1 < TSEQ) ? t + 1 : TSEQ - 1;
        int tok_n = x[(size_t)gn * TSEQ + tn];
        float e_n = e2[(size_t)tok_n * HDIM + jcol];

        if (t > 0) {
            // wait for the 32 producers of this XCD (step t-1): RELAXED polls
            unsigned* f = flags + (size_t)(t - 1) * 256 + xcd * 32 + (lane & 31);
            while (!__all((int)(__hip_atomic_load(f, __ATOMIC_RELAXED,
                                                  __HIP_MEMORY_SCOPE_AGENT) != 0u)))
                __builtin_amdgcn_s_sleep(1);
            // one invalidate so cached h loads below can't hit stale L1/L2
            __builtin_amdgcn_fence(__ATOMIC_ACQUIRE, "agent");
        }
        const _Float16* hin_hi  = hbuf + (size_t)( t      & 1) * HBUFSZ;
        const _Float16* hin_lo  = hin_hi + HPLANE;
        _Float16*       hout_hi = hbuf + (size_t)((t + 1) & 1) * HBUFSZ;
        _Float16*       hout_lo = hout_hi + HPLANE;

        // ---- A loads: 32 cached 16B loads, one drain (rows gbase..+7 dup'd)
        const _Float16* AbH = hin_hi + (size_t)(gbase + rowA) * HDIM + p * 512 + lq * 8;
        const _Float16* AbL = hin_lo + (size_t)(gbase + rowA) * HDIM + p * 512 + lq * 8;
        f16x8 ah0[8], al0[8], ah1[8], al1[8];
        LOADA32(ah0, al0, ah1, al1, AbH, AbL, AbH + 256, AbL + 256);

        // ---- MFMA: wave (p,ct): k in [p*512, +512)
        f32x4 acc0 = {0.f, 0.f, 0.f, 0.f};
        f32x4 acc1 = {0.f, 0.f, 0.f, 0.f};
        #pragma unroll
        for (int mi = 0; mi < 8; ++mi) {
            const int m = p * 16 + mi;
            f16x8 bh2 = *(const f16x8*)&bls[0][m][ct][lane][0];
            f16x8 bl2 = *(const f16x8*)&bls[1][m][ct][lane][0];
            acc0 = __builtin_amdgcn_mfma_f32_16x16x32_f16(ah0[mi], bh2, acc0, 0, 0, 0);
            acc1 = __builtin_amdgcn_mfma_f32_16x16x32_f16(al0[mi], bh2, acc1, 0, 0, 0);
            acc1 = __builtin_amdgcn_mfma_f32_16x16x32_f16(ah0[mi], bl2, acc1, 0, 0, 0);
        }
        #pragma unroll
        for (int mi = 0; mi < 8; ++mi) {
            const int m = p * 16 + 8 + mi;
            f16x8 bh2 = *(const f16x8*)&bls[0][m][ct][lane][0];
            f16x8 bl2 = *(const f16x8*)&bls[1][m][ct][lane][0];
            acc0 = __builtin_amdgcn_mfma_f32_16x16x32_f16(ah1[mi], bh2, acc0, 0, 0, 0);
            acc1 = __builtin_amdgcn_mfma_f32_16x16x32_f16(al1[mi], bh2, acc1, 0, 0, 0);
            acc1 = __builtin_amdgcn_mfma_f32_16x16x32_f16(ah1[mi], bl2, acc1, 0, 0, 0);
        }
        f32x4 part;
        #pragma unroll
        for (int r = 0; r < 4; ++r) part[r] = acc0[r] + acc1[r] * LOINV;
        red[w][lane] = part;
        __syncthreads();

        // ---- epilogue: thread -> (erow, ecol)
        float s = ((const float*)&red[ctE][laneE])[rE]
                + ((const float*)&red[2 + ctE][laneE])[rE];
        float pre = s + ev;
        float hv  = tanhf(pre);
        _Float16 h16 = (_Float16)hv;
        _Float16 l16 = (_Float16)((hv - (float)h16) * LOSCALE);

        z[(size_t)(t - t0) * HPLANE + (size_t)gn * HDIM + jcol] = h16;  // cached
        if (t == TSEQ - 1) hlast_out[(size_t)gn * HDIM + jcol] = hv;    // cached

        {   // h exchange: sc0 sc1 -> coherence point; drain via vmcnt(0)
            union { _Float16 f; unsigned short u; } uh{h16}, ul{l16};
            unsigned vh = uh.u, vl = ul.u;
            const _Float16* ph = hout_hi + (size_t)gn * HDIM + jcol;
            const _Float16* pl = hout_lo + (size_t)gn * HDIM + jcol;
            asm volatile("global_store_short %0, %2, off sc0 sc1\n\t"
                         "global_store_short %1, %3, off sc0 sc1\n\t"
                         "s_waitcnt vmcnt(0)"
                         :: "v"(ph), "v"(pl), "v"(vh), "v"(vl) : "memory");
        }
        __syncthreads();           // all 256 h values of this WG are visible
        if (tid == 0)
            __hip_atomic_store(&flags[(size_t)t * 256 + xcd * 32 + slot], 1u,
                               __ATOMIC_RELAXED, __HIP_MEMORY_SCOPE_AGENT);
        tokv = tok_n; ev = e_n;
    }
}

// ---------------------------------------------------------------- output GEMM + softmax
__global__ __launch_bounds__(256, 1) void rnn_out(
    const _Float16* __restrict__ z,      // chunk: [tc][NSEQ*HDIM]
    const _Float16* __restrict__ woutT,  // [ODIM][HDIM]
    const float* __restrict__ bout,      // [ODIM]
    float* __restrict__ y,               // [NSEQ][TSEQ][ODIM]
    int t0, int tc)
{
    const int b = blockIdx.x;
    const int t_rel = b >> 2, ng = b & 3;
    const int t = t0 + t_rel;
    const int n0 = ng * 16;
    const int tid = threadIdx.x;
    const int lane = tid & 63, wv = tid >> 6;
    const int lr = lane & 15, lq = lane >> 4;

    __shared__ float lg[16][ODIM + 8];   // logits staging

    const _Float16* abase = z + (size_t)t_rel * (NSEQ * HDIM)
                              + (size_t)(n0 + lr) * HDIM + lq * 8;
    f16x8 af[32];
    #pragma unroll
    for (int m = 0; m < 32; ++m) af[m] = *(const f16x8*)(abase + m * 32);

    #pragma unroll
    for (int i = 0; i < 4; ++i) {
        int ot = (wv * 4 + i) * 16;
        const _Float16* bbase = woutT + (size_t)(ot + lr) * HDIM + lq * 8;
        f32x4 acc = {0.f, 0.f, 0.f, 0.f};
        #pragma unroll
        for (int m = 0; m < 32; ++m) {
            f16x8 bfr = *(const f16x8*)(bbase + m * 32);
            acc = __builtin_amdgcn_mfma_f32_16x16x32_f16(af[m], bfr, acc, 0, 0, 0);
        }
        #pragma unroll
        for (int r = 0; r < 4; ++r)
            lg[lq * 4 + r][ot + lr] = acc[r];
    }
    __syncthreads();

    for (int rr = 0; rr < 4; ++rr) {
        int row = wv * 4 + rr;
        int n = n0 + row;
        float v0 = lg[row][lane]       + bout[lane];
        float v1 = lg[row][64 + lane]  + bout[64 + lane];
        float v2 = lg[row][128 + lane] + bout[128 + lane];
        float v3 = lg[row][192 + lane] + bout[192 + lane];
        float mx = fmaxf(fmaxf(v0, v1), fmaxf(v2, v3));
        for (int s = 32; s > 0; s >>= 1) mx = fmaxf(mx, __shfl_xor(mx, s));
        float e0 = __expf(v0 - mx), e1 = __expf(v1 - mx);
        float e2v = __expf(v2 - mx), e3 = __expf(v3 - mx);
        float sm = e0 + e1 + e2v + e3;
        for (int s = 32; s > 0; s >>= 1) sm += __shfl_xor(sm, s);
        float inv = 1.f / sm;
        float* dst = y + ((size_t)n * TSEQ + t) * ODIM;
        dst[lane]       = e0 * inv;
        dst[64 + lane]  = e1 * inv;
        dst[128 + lane] = e2v * inv;
        dst[192 + lane] = e3 * inv;
    }
}

// ---------------------------------------------------------------- launch
extern "C" void kernel_launch(void* const* d_in, const int* in_sizes, int n_in,
                              void* d_out, int out_size, void* d_ws, size_t ws_size,
                              hipStream_t stream)
{
    const int*   x    = (const int*)  d_in[0];
    const float* E    = (const float*)d_in[1];
    const float* Whh  = (const float*)d_in[2];
    const float* bh   = (const float*)d_in[3];
    const float* Wout = (const float*)d_in[4];
    const float* bout = (const float*)d_in[5];

    float* y     = (float*)d_out;
    float* hlast = y + (size_t)NSEQ * TSEQ * ODIM;

    char* ws = (char*)d_ws;
    size_t off = 0;
    auto alloc = [&](size_t bytes) -> void* {
        void* p = ws + off;
        off = (off + bytes + 255) & ~(size_t)255;
        return p;
    };
    _Float16* whhT_hi = (_Float16*)alloc((size_t)HDIM * HDIM * 2);
    _Float16* whhT_lo = (_Float16*)alloc((size_t)HDIM * HDIM * 2);
    _Float16* woutT   = (_Float16*)alloc((size_t)ODIM * HDIM * 2);
    float*    e2      = (float*)   alloc((size_t)VOCABSZ * HDIM * 4);
    _Float16* hbuf    = (_Float16*)alloc((size_t)2 * HBUFSZ * 2);
    unsigned* flags   = (unsigned*)alloc((size_t)TSEQ * 256 * 4);
    unsigned* claims  = (unsigned*)alloc((size_t)64 * 8 * 4);
    _Float16* z       = (_Float16*)(ws + off);

    size_t zcap = (ws_size > off) ? (ws_size - off) : 0;
    int tc_max = (int)(zcap / ((size_t)NSEQ * HDIM * 2));
    if (tc_max > TSEQ) tc_max = TSEQ;
    if (tc_max < 1)    tc_max = 1;

    rnn_init<<<2048, 256, 0, stream>>>(Whh, Wout, E, bh, whhT_hi, whhT_lo,
                                       woutT, e2, hbuf, flags, claims);

    int chunk = 0;
    for (int t0 = 0; t0 < TSEQ; t0 += tc_max, ++chunk) {
        int tc = TSEQ - t0 < tc_max ? TSEQ - t0 : tc_max;
        rnn_steps<<<1024, 256, 0, stream>>>(x, e2, whhT_hi, whhT_lo, hbuf,
                                            flags, claims + (chunk & 63) * 8,
                                            z, hlast, t0, t0 + tc);
        rnn_out<<<tc * 4, 256, 0, stream>>>(z, woutT, bout, y, t0, tc);
    }
}

// Round 12
// 6150.779 us; speedup vs baseline: 2.2076x; 2.2076x over previous
//
#include <hip/hip_runtime.h>

// RNN: h_t = tanh(E[x_t] + h_{t-1} @ Whh + bh), T=1024, N=64, H=1024.
// y = softmax(z @ Wout + bout). Output: y (64*1024*256 f32) then h_last (64*1024 f32).
//
// Double-FP16 recurrence (hi + 2^-11*lo of h and Whh) -> fp32-equivalent
// per-step precision (R3..R11: passed, absmax 9.8e-4).
//
// R12 = R11 minus the per-step agent-acquire fence ("fence-free L3 protocol").
// R11's fence cost dominated: acquire = vmcnt drain (blocked on loop-top
// prefetch loads, ~1 L3 RT) + L1/L2 invalidate (forced z writeback storm +
// every x/e2 access L2-missing afterwards), x256 WGs x1024 steps.
// Fix: consumers read h with sc0 sc1 loads (L1/L2-bypass, straight from L3 =
// the same coherence point producers drain to before setting their flag).
// No fence, no invalidate; x/e2/z stay warm in L1/L2.
// Everything else identical to R11: 8 seqs/XCD (XCC_ID claim), 32 WGs/XCD,
// 32 cols/WG, Whh hi/lo slice in 128 KB LDS, 32 A-loads in one asm batch
// with a single vmcnt(0), 1-output/thread epilogue, relaxed atomic flags.

typedef _Float16 f16x8 __attribute__((ext_vector_type(8)));
typedef float    f32x4 __attribute__((ext_vector_type(4)));

#define NSEQ  64
#define TSEQ  1024
#define HDIM  1024
#define VOCABSZ 256
#define ODIM  256
#define LOSCALE 2048.0f
#define LOINV  (1.0f/2048.0f)

// hbuf layout: [buf(2)][plane(2: hi,lo)][NSEQ][HDIM] fp16
#define HPLANE (NSEQ * HDIM)
#define HBUFSZ (2 * HPLANE)

// ---------------------------------------------------------------- init / prep
__global__ __launch_bounds__(256) void rnn_init(
    const float* __restrict__ Whh, const float* __restrict__ Wout,
    const float* __restrict__ E,   const float* __restrict__ bh,
    _Float16* __restrict__ whhT_hi, _Float16* __restrict__ whhT_lo,
    _Float16* __restrict__ woutT,  float* __restrict__ e2,
    _Float16* __restrict__ hbuf, unsigned* __restrict__ flags,
    unsigned* __restrict__ claims)
{
    int i = blockIdx.x * 256 + threadIdx.x;
    int stride = gridDim.x * 256;
    for (int idx = i; idx < HDIM * HDIM; idx += stride) {
        int j = idx >> 10, k = idx & 1023;
        float w = Whh[k * HDIM + j];
        _Float16 hi = (_Float16)w;
        whhT_hi[idx] = hi;
        whhT_lo[idx] = (_Float16)((w - (float)hi) * LOSCALE);
    }
    for (int idx = i; idx < ODIM * HDIM; idx += stride) {
        int o = idx >> 10, k = idx & 1023;
        woutT[idx] = (_Float16)Wout[k * ODIM + o];
    }
    for (int idx = i; idx < VOCABSZ * HDIM; idx += stride) {
        int j = idx & 1023;
        e2[idx] = E[idx] + bh[j];
    }
    for (int idx = i; idx < 2 * HBUFSZ; idx += stride) hbuf[idx] = (_Float16)0.f;
    for (int idx = i; idx < TSEQ * 256; idx += stride) flags[idx] = 0u;
    for (int idx = i; idx < 64 * 8; idx += stride) claims[idx] = 0u;
}

// ---------------------------------------------------------------- recurrence
// 32 L3-direct loads (sc0 sc1, 16B each) back-to-back, ONE vmcnt(0) drain.
// Early-clobber outputs (written while the 4 address pairs are still live).
#define LOADA32(AH0, AL0, AH1, AL1, B0, B1, B2, B3)                          \
    asm volatile(                                                            \
        "global_load_dwordx4 %[a0], %[q0], off sc0 sc1\n\t"                  \
        "global_load_dwordx4 %[a1], %[q0], off offset:64 sc0 sc1\n\t"        \
        "global_load_dwordx4 %[a2], %[q0], off offset:128 sc0 sc1\n\t"       \
        "global_load_dwordx4 %[a3], %[q0], off offset:192 sc0 sc1\n\t"       \
        "global_load_dwordx4 %[a4], %[q0], off offset:256 sc0 sc1\n\t"       \
        "global_load_dwordx4 %[a5], %[q0], off offset:320 sc0 sc1\n\t"       \
        "global_load_dwordx4 %[a6], %[q0], off offset:384 sc0 sc1\n\t"       \
        "global_load_dwordx4 %[a7], %[q0], off offset:448 sc0 sc1\n\t"       \
        "global_load_dwordx4 %[b0], %[q1], off sc0 sc1\n\t"                  \
        "global_load_dwordx4 %[b1], %[q1], off offset:64 sc0 sc1\n\t"        \
        "global_load_dwordx4 %[b2], %[q1], off offset:128 sc0 sc1\n\t"       \
        "global_load_dwordx4 %[b3], %[q1], off offset:192 sc0 sc1\n\t"       \
        "global_load_dwordx4 %[b4], %[q1], off offset:256 sc0 sc1\n\t"       \
        "global_load_dwordx4 %[b5], %[q1], off offset:320 sc0 sc1\n\t"       \
        "global_load_dwordx4 %[b6], %[q1], off offset:384 sc0 sc1\n\t"       \
        "global_load_dwordx4 %[b7], %[q1], off offset:448 sc0 sc1\n\t"       \
        "global_load_dwordx4 %[c0], %[q2], off sc0 sc1\n\t"                  \
        "global_load_dwordx4 %[c1], %[q2], off offset:64 sc0 sc1\n\t"        \
        "global_load_dwordx4 %[c2], %[q2], off offset:128 sc0 sc1\n\t"       \
        "global_load_dwordx4 %[c3], %[q2], off offset:192 sc0 sc1\n\t"       \
        "global_load_dwordx4 %[c4], %[q2], off offset:256 sc0 sc1\n\t"       \
        "global_load_dwordx4 %[c5], %[q2], off offset:320 sc0 sc1\n\t"       \
        "global_load_dwordx4 %[c6], %[q2], off offset:384 sc0 sc1\n\t"       \
        "global_load_dwordx4 %[c7], %[q2], off offset:448 sc0 sc1\n\t"       \
        "global_load_dwordx4 %[d0], %[q3], off sc0 sc1\n\t"                  \
        "global_load_dwordx4 %[d1], %[q3], off offset:64 sc0 sc1\n\t"        \
        "global_load_dwordx4 %[d2], %[q3], off offset:128 sc0 sc1\n\t"       \
        "global_load_dwordx4 %[d3], %[q3], off offset:192 sc0 sc1\n\t"       \
        "global_load_dwordx4 %[d4], %[q3], off offset:256 sc0 sc1\n\t"       \
        "global_load_dwordx4 %[d5], %[q3], off offset:320 sc0 sc1\n\t"       \
        "global_load_dwordx4 %[d6], %[q3], off offset:384 sc0 sc1\n\t"       \
        "global_load_dwordx4 %[d7], %[q3], off offset:448 sc0 sc1\n\t"       \
        "s_waitcnt vmcnt(0)"                                                 \
        : [a0]"=&v"(AH0[0]), [a1]"=&v"(AH0[1]), [a2]"=&v"(AH0[2]),           \
          [a3]"=&v"(AH0[3]), [a4]"=&v"(AH0[4]), [a5]"=&v"(AH0[5]),           \
          [a6]"=&v"(AH0[6]), [a7]"=&v"(AH0[7]),                              \
          [b0]"=&v"(AL0[0]), [b1]"=&v"(AL0[1]), [b2]"=&v"(AL0[2]),           \
          [b3]"=&v"(AL0[3]), [b4]"=&v"(AL0[4]), [b5]"=&v"(AL0[5]),           \
          [b6]"=&v"(AL0[6]), [b7]"=&v"(AL0[7]),                              \
          [c0]"=&v"(AH1[0]), [c1]"=&v"(AH1[1]), [c2]"=&v"(AH1[2]),           \
          [c3]"=&v"(AH1[3]), [c4]"=&v"(AH1[4]), [c5]"=&v"(AH1[5]),           \
          [c6]"=&v"(AH1[6]), [c7]"=&v"(AH1[7]),                              \
          [d0]"=&v"(AL1[0]), [d1]"=&v"(AL1[1]), [d2]"=&v"(AL1[2]),           \
          [d3]"=&v"(AL1[3]), [d4]"=&v"(AL1[4]), [d5]"=&v"(AL1[5]),           \
          [d6]"=&v"(AL1[6]), [d7]"=&v"(AL1[7])                               \
        : [q0]"v"(B0), [q1]"v"(B1), [q2]"v"(B2), [q3]"v"(B3) : "memory")

__global__ __launch_bounds__(256, 1) void rnn_steps(
    const int*   __restrict__ x,          // [NSEQ][TSEQ]
    const float* __restrict__ e2,         // [VOCAB][HDIM]  (E + bh)
    const _Float16* __restrict__ whhT_hi, // [HDIM][HDIM] j-major
    const _Float16* __restrict__ whhT_lo,
    _Float16* __restrict__ hbuf,
    unsigned* __restrict__ flags,         // [TSEQ][8 xcd][32 slot]
    unsigned* __restrict__ claims,        // [8] for this chunk
    _Float16* __restrict__ z,             // chunk: [tc][NSEQ*HDIM]
    float* __restrict__ hlast_out,        // [NSEQ*HDIM]
    int t0, int t1)
{
    const int tid  = threadIdx.x;
    const int lane = tid & 63;
    const int w    = tid >> 6;         // wave 0..3
    const int lq   = lane >> 4;        // k sub-chunk 0..3

    __shared__ _Float16 bls[2][32][2][64][8];  // 128 KB Whh^T frags hi/lo
    __shared__ f32x4    red[4][64];            //   4 KB wave partials
    __shared__ int      slot_s;
    __shared__ unsigned xcd_s;

    // ---- claim a worker slot on this physical XCD
    if (tid == 0) {
        unsigned xcd;
        asm volatile("s_getreg_b32 %0, hwreg(HW_REG_XCC_ID)" : "=s"(xcd));
        xcd &= 7;
        xcd_s  = xcd;
        slot_s = (int)atomicAdd(&claims[xcd], 1u);
    }
    __syncthreads();
    const int slot = slot_s;
    if (slot >= 32) return;            // surplus block
    const unsigned xcd = xcd_s;
    const int gbase = (int)xcd * 8;    // this XCD's 8 sequences
    const int j0c   = slot * 32;       // this WG's 32 columns

    // ---- one-time: stage B fragments (32 cols, hi+lo) into LDS
    for (int idx = tid; idx < 8192; idx += 256) {
        int l   = idx & 63;
        int ct_ = (idx >> 6) & 1;
        int m   = (idx >> 7) & 31;
        int pl_ = idx >> 12;
        int col = j0c + ct_ * 16 + (l & 15);
        int k   = m * 32 + (l >> 4) * 8;
        const _Float16* s = (pl_ ? whhT_lo : whhT_hi) + (size_t)col * HDIM + k;
        *(f16x8*)&bls[pl_][m][ct_][l][0] = *(const f16x8*)s;
    }
    __syncthreads();

    const int ct = w & 1, p = w >> 1;  // col-tile, k-half of this wave
    const int rowA = lane & 7;

    // epilogue role: one output value per thread
    const int erow = tid >> 5;         // 0..7
    const int ecol = tid & 31;         // 0..31
    const int gn   = gbase + erow;
    const int jcol = j0c + ecol;
    const int ctE  = ecol >> 4;
    const int laneE= ((erow >> 2) << 4) | (ecol & 15);
    const int rE   = erow & 3;

    int   tokv = x[(size_t)gn * TSEQ + t0];
    float ev   = e2[(size_t)tokv * HDIM + jcol];

    for (int t = t0; t < t1; ++t) {
        // prefetch next step's token + E value (read-only, cached)
        int tn = (t + 1 < TSEQ) ? t + 1 : TSEQ - 1;
        int tok_n = x[(size_t)gn * TSEQ + tn];
        float e_n = e2[(size_t)tok_n * HDIM + jcol];

        if (t > 0) {
            // wait for the 32 producers of this XCD (step t-1): RELAXED polls.
            // No fence needed: h is read L3-direct (sc0 sc1) below, and
            // producers drained h to L3 before setting their flag.
            unsigned* f = flags + (size_t)(t - 1) * 256 + xcd * 32 + (lane & 31);
            while (!__all((int)(__hip_atomic_load(f, __ATOMIC_RELAXED,
                                                  __HIP_MEMORY_SCOPE_AGENT) != 0u)))
                __builtin_amdgcn_s_sleep(1);
        }
        const _Float16* hin_hi  = hbuf + (size_t)( t      & 1) * HBUFSZ;
        const _Float16* hin_lo  = hin_hi + HPLANE;
        _Float16*       hout_hi = hbuf + (size_t)((t + 1) & 1) * HBUFSZ;
        _Float16*       hout_lo = hout_hi + HPLANE;

        // ---- A loads: 32 L3-direct 16B loads, one drain
        const _Float16* AbH = hin_hi + (size_t)(gbase + rowA) * HDIM + p * 512 + lq * 8;
        const _Float16* AbL = hin_lo + (size_t)(gbase + rowA) * HDIM + p * 512 + lq * 8;
        f16x8 ah0[8], al0[8], ah1[8], al1[8];
        LOADA32(ah0, al0, ah1, al1, AbH, AbL, AbH + 256, AbL + 256);

        // ---- MFMA: wave (p,ct): k in [p*512, +512)
        f32x4 acc0 = {0.f, 0.f, 0.f, 0.f};
        f32x4 acc1 = {0.f, 0.f, 0.f, 0.f};
        #pragma unroll
        for (int mi = 0; mi < 8; ++mi) {
            const int m = p * 16 + mi;
            f16x8 bh2 = *(const f16x8*)&bls[0][m][ct][lane][0];
            f16x8 bl2 = *(const f16x8*)&bls[1][m][ct][lane][0];
            acc0 = __builtin_amdgcn_mfma_f32_16x16x32_f16(ah0[mi], bh2, acc0, 0, 0, 0);
            acc1 = __builtin_amdgcn_mfma_f32_16x16x32_f16(al0[mi], bh2, acc1, 0, 0, 0);
            acc1 = __builtin_amdgcn_mfma_f32_16x16x32_f16(ah0[mi], bl2, acc1, 0, 0, 0);
        }
        #pragma unroll
        for (int mi = 0; mi < 8; ++mi) {
            const int m = p * 16 + 8 + mi;
            f16x8 bh2 = *(const f16x8*)&bls[0][m][ct][lane][0];
            f16x8 bl2 = *(const f16x8*)&bls[1][m][ct][lane][0];
            acc0 = __builtin_amdgcn_mfma_f32_16x16x32_f16(ah1[mi], bh2, acc0, 0, 0, 0);
            acc1 = __builtin_amdgcn_mfma_f32_16x16x32_f16(al1[mi], bh2, acc1, 0, 0, 0);
            acc1 = __builtin_amdgcn_mfma_f32_16x16x32_f16(ah1[mi], bl2, acc1, 0, 0, 0);
        }
        f32x4 part;
        #pragma unroll
        for (int r = 0; r < 4; ++r) part[r] = acc0[r] + acc1[r] * LOINV;
        red[w][lane] = part;
        __syncthreads();

        // ---- epilogue: thread -> (erow, ecol)
        float s = ((const float*)&red[ctE][laneE])[rE]
                + ((const float*)&red[2 + ctE][laneE])[rE];
        float pre = s + ev;
        float hv  = tanhf(pre);
        _Float16 h16 = (_Float16)hv;
        _Float16 l16 = (_Float16)((hv - (float)h16) * LOSCALE);

        z[(size_t)(t - t0) * HPLANE + (size_t)gn * HDIM + jcol] = h16;  // cached
        if (t == TSEQ - 1) hlast_out[(size_t)gn * HDIM + jcol] = hv;    // cached

        {   // h exchange: sc0 sc1 -> L3 coherence point; drain via vmcnt(0)
            union { _Float16 f; unsigned short u; } uh{h16}, ul{l16};
            unsigned vh = uh.u, vl = ul.u;
            const _Float16* ph = hout_hi + (size_t)gn * HDIM + jcol;
            const _Float16* pl = hout_lo + (size_t)gn * HDIM + jcol;
            asm volatile("global_store_short %0, %2, off sc0 sc1\n\t"
                         "global_store_short %1, %3, off sc0 sc1\n\t"
                         "s_waitcnt vmcnt(0)"
                         :: "v"(ph), "v"(pl), "v"(vh), "v"(vl) : "memory");
        }
        __syncthreads();           // all 256 h values of this WG are at L3
        if (tid == 0)
            __hip_atomic_store(&flags[(size_t)t * 256 + xcd * 32 + slot], 1u,
                               __ATOMIC_RELAXED, __HIP_MEMORY_SCOPE_AGENT);
        tokv = tok_n; ev = e_n;
    }
}

// ---------------------------------------------------------------- output GEMM + softmax
__global__ __launch_bounds__(256, 1) void rnn_out(
    const _Float16* __restrict__ z,      // chunk: [tc][NSEQ*HDIM]
    const _Float16* __restrict__ woutT,  // [ODIM][HDIM]
    const float* __restrict__ bout,      // [ODIM]
    float* __restrict__ y,               // [NSEQ][TSEQ][ODIM]
    int t0, int tc)
{
    const int b = blockIdx.x;
    const int t_rel = b >> 2, ng = b & 3;
    const int t = t0 + t_rel;
    const int n0 = ng * 16;
    const int tid = threadIdx.x;
    const int lane = tid & 63, wv = tid >> 6;
    const int lr = lane & 15, lq = lane >> 4;

    __shared__ float lg[16][ODIM + 8];   // logits staging

    const _Float16* abase = z + (size_t)t_rel * (NSEQ * HDIM)
                              + (size_t)(n0 + lr) * HDIM + lq * 8;
    f16x8 af[32];
    #pragma unroll
    for (int m = 0; m < 32; ++m) af[m] = *(const f16x8*)(abase + m * 32);

    #pragma unroll
    for (int i = 0; i < 4; ++i) {
        int ot = (wv * 4 + i) * 16;
        const _Float16* bbase = woutT + (size_t)(ot + lr) * HDIM + lq * 8;
        f32x4 acc = {0.f, 0.f, 0.f, 0.f};
        #pragma unroll
        for (int m = 0; m < 32; ++m) {
            f16x8 bfr = *(const f16x8*)(bbase + m * 32);
            acc = __builtin_amdgcn_mfma_f32_16x16x32_f16(af[m], bfr, acc, 0, 0, 0);
        }
        #pragma unroll
        for (int r = 0; r < 4; ++r)
            lg[lq * 4 + r][ot + lr] = acc[r];
    }
    __syncthreads();

    for (int rr = 0; rr < 4; ++rr) {
        int row = wv * 4 + rr;
        int n = n0 + row;
        float v0 = lg[row][lane]       + bout[lane];
        float v1 = lg[row][64 + lane]  + bout[64 + lane];
        float v2 = lg[row][128 + lane] + bout[128 + lane];
        float v3 = lg[row][192 + lane] + bout[192 + lane];
        float mx = fmaxf(fmaxf(v0, v1), fmaxf(v2, v3));
        for (int s = 32; s > 0; s >>= 1) mx = fmaxf(mx, __shfl_xor(mx, s));
        float e0 = __expf(v0 - mx), e1 = __expf(v1 - mx);
        float e2v = __expf(v2 - mx), e3 = __expf(v3 - mx);
        float sm = e0 + e1 + e2v + e3;
        for (int s = 32; s > 0; s >>= 1) sm += __shfl_xor(sm, s);
        float inv = 1.f / sm;
        float* dst = y + ((size_t)n * TSEQ + t) * ODIM;
        dst[lane]       = e0 * inv;
        dst[64 + lane]  = e1 * inv;
        dst[128 + lane] = e2v * inv;
        dst[192 + lane] = e3 * inv;
    }
}

// ---------------------------------------------------------------- launch
extern "C" void kernel_launch(void* const* d_in, const int* in_sizes, int n_in,
                              void* d_out, int out_size, void* d_ws, size_t ws_size,
                              hipStream_t stream)
{
    const int*   x    = (const int*)  d_in[0];
    const float* E    = (const float*)d_in[1];
    const float* Whh  = (const float*)d_in[2];
    const float* bh   = (const float*)d_in[3];
    const float* Wout = (const float*)d_in[4];
    const float* bout = (const float*)d_in[5];

    float* y     = (float*)d_out;
    float* hlast = y + (size_t)NSEQ * TSEQ * ODIM;

    char* ws = (char*)d_ws;
    size_t off = 0;
    auto alloc = [&](size_t bytes) -> void* {
        void* p = ws + off;
        off = (off + bytes + 255) & ~(size_t)255;
        return p;
    };
    _Float16* whhT_hi = (_Float16*)alloc((size_t)HDIM * HDIM * 2);
    _Float16* whhT_lo = (_Float16*)alloc((size_t)HDIM * HDIM * 2);
    _Float16* woutT   = (_Float16*)alloc((size_t)ODIM * HDIM * 2);
    float*    e2      = (float*)   alloc((size_t)VOCABSZ * HDIM * 4);
    _Float16* hbuf    = (_Float16*)alloc((size_t)2 * HBUFSZ * 2);
    unsigned* flags   = (unsigned*)alloc((size_t)TSEQ * 256 * 4);
    unsigned* claims  = (unsigned*)alloc((size_t)64 * 8 * 4);
    _Float16* z       = (_Float16*)(ws + off);

    size_t zcap = (ws_size > off) ? (ws_size - off) : 0;
    int tc_max = (int)(zcap / ((size_t)NSEQ * HDIM * 2));
    if (tc_max > TSEQ) tc_max = TSEQ;
    if (tc_max < 1)    tc_max = 1;

    rnn_init<<<2048, 256, 0, stream>>>(Whh, Wout, E, bh, whhT_hi, whhT_lo,
                                       woutT, e2, hbuf, flags, claims);

    int chunk = 0;
    for (int t0 = 0; t0 < TSEQ; t0 += tc_max, ++chunk) {
        int tc = TSEQ - t0 < tc_max ? TSEQ - t0 : tc_max;
        rnn_steps<<<1024, 256, 0, stream>>>(x, e2, whhT_hi, whhT_lo, hbuf,
                                            flags, claims + (chunk & 63) * 8,
                                            z, hlast, t0, t0 + tc);
        rnn_out<<<tc * 4, 256, 0, stream>>>(z, woutT, bout, y, t0, tc);
    }
}

// Round 16
// 5737.586 us; speedup vs baseline: 2.3665x; 1.0720x over previous
//
#include <hip/hip_runtime.h>

// RNN: h_t = tanh(E[x_t] + h_{t-1} @ Whh + bh), T=1024, N=64, H=1024.
// y = softmax(z @ Wout + bout). Output: y (64*1024*256 f32) then h_last (64*1024 f32).
//
// Double-FP16 recurrence (hi + 2^-11*lo of h and Whh) -> fp32-equivalent
// per-step precision (R3..R12: passed, absmax 9.8e-4).
//
// Protocol law (R10/R12/R13 evidence):
//  - h DATA: sc0 sc1 stores/loads (L3 coherence point) + vmcnt(0) drain.
//  - SYNC: atomics only (relaxed, agent scope). R13's sc0 flag/poll HUNG:
//    plain sub-L3 ops carry no cross-CU visibility obligation.
//
// R14 = R12 + (1) wave = k-quarter covering BOTH col-tiles: per-lane A-loads
// 32->16, halves L3 A-traffic (R12's col-tile waves loaded identical A);
// (2) counter flags: each WAVE atomicAdds cnt[t][xcd][quarter] after its own
// drain (lockstep wave => drain precedes add); consumer polls ONE dword to 32
// (8 WGs x 4 waves). Second __syncthreads removed; (3) red[] double-buffered
// by step parity (race-free with the single remaining barrier).

typedef _Float16 f16x8 __attribute__((ext_vector_type(8)));
typedef float    f32x4 __attribute__((ext_vector_type(4)));

#define NSEQ  64
#define TSEQ  1024
#define HDIM  1024
#define VOCABSZ 256
#define ODIM  256
#define LOSCALE 2048.0f
#define LOINV  (1.0f/2048.0f)

// hbuf layout: [buf(2)][plane(2: hi,lo)][NSEQ][HDIM] fp16
#define HPLANE (NSEQ * HDIM)
#define HBUFSZ (2 * HPLANE)

// ---------------------------------------------------------------- init / prep
__global__ __launch_bounds__(256) void rnn_init(
    const float* __restrict__ Whh, const float* __restrict__ Wout,
    const float* __restrict__ E,   const float* __restrict__ bh,
    _Float16* __restrict__ whhT_hi, _Float16* __restrict__ whhT_lo,
    _Float16* __restrict__ woutT,  float* __restrict__ e2,
    _Float16* __restrict__ hbuf, unsigned* __restrict__ flags,
    unsigned* __restrict__ claims)
{
    int i = blockIdx.x * 256 + threadIdx.x;
    int stride = gridDim.x * 256;
    for (int idx = i; idx < HDIM * HDIM; idx += stride) {
        int j = idx >> 10, k = idx & 1023;
        float w = Whh[k * HDIM + j];
        _Float16 hi = (_Float16)w;
        whhT_hi[idx] = hi;
        whhT_lo[idx] = (_Float16)((w - (float)hi) * LOSCALE);
    }
    for (int idx = i; idx < ODIM * HDIM; idx += stride) {
        int o = idx >> 10, k = idx & 1023;
        woutT[idx] = (_Float16)Wout[k * ODIM + o];
    }
    for (int idx = i; idx < VOCABSZ * HDIM; idx += stride) {
        int j = idx & 1023;
        e2[idx] = E[idx] + bh[j];
    }
    for (int idx = i; idx < 2 * HBUFSZ; idx += stride) hbuf[idx] = (_Float16)0.f;
    for (int idx = i; idx < TSEQ * 32; idx += stride) flags[idx] = 0u;
    for (int idx = i; idx < 64 * 8; idx += stride) claims[idx] = 0u;
}

// ---------------------------------------------------------------- recurrence
// 16 L3-direct loads (sc0 sc1, 16B each, stride 64B) + single vmcnt drain.
// EARLY-CLOBBER outputs (written while [bh]/[bl] still live).
#define LOADA(AH, AL, BH_, BL_)                                              \
    asm volatile(                                                            \
        "global_load_dwordx4 %[o0], %[bh], off sc0 sc1\n\t"                  \
        "global_load_dwordx4 %[o1], %[bh], off offset:64 sc0 sc1\n\t"        \
        "global_load_dwordx4 %[o2], %[bh], off offset:128 sc0 sc1\n\t"       \
        "global_load_dwordx4 %[o3], %[bh], off offset:192 sc0 sc1\n\t"       \
        "global_load_dwordx4 %[o4], %[bh], off offset:256 sc0 sc1\n\t"       \
        "global_load_dwordx4 %[o5], %[bh], off offset:320 sc0 sc1\n\t"       \
        "global_load_dwordx4 %[o6], %[bh], off offset:384 sc0 sc1\n\t"       \
        "global_load_dwordx4 %[o7], %[bh], off offset:448 sc0 sc1\n\t"       \
        "global_load_dwordx4 %[p0], %[bl], off sc0 sc1\n\t"                  \
        "global_load_dwordx4 %[p1], %[bl], off offset:64 sc0 sc1\n\t"        \
        "global_load_dwordx4 %[p2], %[bl], off offset:128 sc0 sc1\n\t"       \
        "global_load_dwordx4 %[p3], %[bl], off offset:192 sc0 sc1\n\t"       \
        "global_load_dwordx4 %[p4], %[bl], off offset:256 sc0 sc1\n\t"       \
        "global_load_dwordx4 %[p5], %[bl], off offset:320 sc0 sc1\n\t"       \
        "global_load_dwordx4 %[p6], %[bl], off offset:384 sc0 sc1\n\t"       \
        "global_load_dwordx4 %[p7], %[bl], off offset:448 sc0 sc1\n\t"       \
        "s_waitcnt vmcnt(0)"                                                 \
        : [o0]"=&v"(AH[0]), [o1]"=&v"(AH[1]), [o2]"=&v"(AH[2]),              \
          [o3]"=&v"(AH[3]), [o4]"=&v"(AH[4]), [o5]"=&v"(AH[5]),              \
          [o6]"=&v"(AH[6]), [o7]"=&v"(AH[7]),                                \
          [p0]"=&v"(AL[0]), [p1]"=&v"(AL[1]), [p2]"=&v"(AL[2]),              \
          [p3]"=&v"(AL[3]), [p4]"=&v"(AL[4]), [p5]"=&v"(AL[5]),              \
          [p6]"=&v"(AL[6]), [p7]"=&v"(AL[7])                                 \
        : [bh]"v"(BH_), [bl]"v"(BL_) : "memory")

__global__ __launch_bounds__(256, 1) void rnn_steps(
    const int*   __restrict__ x,          // [NSEQ][TSEQ]
    const float* __restrict__ e2,         // [VOCAB][HDIM]  (E + bh)
    const _Float16* __restrict__ whhT_hi, // [HDIM][HDIM] j-major
    const _Float16* __restrict__ whhT_lo,
    _Float16* __restrict__ hbuf,
    unsigned* __restrict__ flags,         // [TSEQ][8 xcd][4 quarter] counters
    unsigned* __restrict__ claims,        // [8] for this chunk
    _Float16* __restrict__ z,             // chunk: [tc][NSEQ*HDIM]
    float* __restrict__ hlast_out,        // [NSEQ*HDIM]
    int t0, int t1)
{
    const int tid  = threadIdx.x;
    const int lane = tid & 63;
    const int w    = tid >> 6;         // wave 0..3 = k-quarter
    const int lq   = lane >> 4;        // k sub-chunk 0..3

    __shared__ _Float16 bls[2][32][2][64][8];  // 128 KB Whh^T frags hi/lo
    __shared__ f32x4    red[2][4][2][64];      //  16 KB partials, dbuf by parity
    __shared__ int      slot_s;
    __shared__ unsigned xcd_s;

    // ---- claim a worker slot on this physical XCD
    if (tid == 0) {
        unsigned xcd;
        asm volatile("s_getreg_b32 %0, hwreg(HW_REG_XCC_ID)" : "=s"(xcd));
        xcd &= 7;
        xcd_s  = xcd;
        slot_s = (int)atomicAdd(&claims[xcd], 1u);
    }
    __syncthreads();
    const int slot = slot_s;
    if (slot >= 32) return;            // surplus block
    const unsigned xcd = xcd_s;
    const int gbase = (int)xcd * 8;    // this XCD's 8 sequences
    const int j0c   = slot * 32;       // this WG's 32 columns
    const int myq   = slot >> 3;       // quarter this WG's columns fall in

    // ---- one-time: stage B fragments (32 cols, hi+lo) into LDS
    for (int idx = tid; idx < 8192; idx += 256) {
        int l   = idx & 63;
        int ct_ = (idx >> 6) & 1;
        int m   = (idx >> 7) & 31;
        int pl_ = idx >> 12;
        int col = j0c + ct_ * 16 + (l & 15);
        int k   = m * 32 + (l >> 4) * 8;
        const _Float16* s = (pl_ ? whhT_lo : whhT_hi) + (size_t)col * HDIM + k;
        *(f16x8*)&bls[pl_][m][ct_][l][0] = *(const f16x8*)s;
    }
    __syncthreads();

    const int rowA = lane & 7;

    // epilogue role: one output value per thread
    const int erow = tid >> 5;         // 0..7
    const int ecol = tid & 31;         // 0..31
    const int gn   = gbase + erow;
    const int jcol = j0c + ecol;
    const int ctE  = ecol >> 4;
    const int laneE= ((erow >> 2) << 4) | (ecol & 15);
    const int rE   = erow & 3;

    int   tokv = x[(size_t)gn * TSEQ + t0];
    float ev   = e2[(size_t)tokv * HDIM + jcol];

    for (int t = t0; t < t1; ++t) {
        const int par = t & 1;
        // prefetch next step's token + E value (read-only, cached)
        int tn = (t + 1 < TSEQ) ? t + 1 : TSEQ - 1;
        int tok_n = x[(size_t)gn * TSEQ + tn];
        float e_n = e2[(size_t)tok_n * HDIM + jcol];

        if (t > 0) {
            // wave w needs quarter w of step t-1: poll ONE counter to 32
            // (8 producer WGs x 4 waves). Atomic (coherence-point) poll --
            // R13 proved plain sc0 polls can hang.
            unsigned* cp = flags + (size_t)(t - 1) * 32 + xcd * 4 + w;
            while (__hip_atomic_load(cp, __ATOMIC_RELAXED,
                                     __HIP_MEMORY_SCOPE_AGENT) < 32u)
                __builtin_amdgcn_s_sleep(1);
        }
        const _Float16* hin_hi  = hbuf + (size_t)( t      & 1) * HBUFSZ;
        const _Float16* hin_lo  = hin_hi + HPLANE;
        _Float16*       hout_hi = hbuf + (size_t)((t + 1) & 1) * HBUFSZ;
        _Float16*       hout_lo = hout_hi + HPLANE;

        // ---- A loads: wave w covers k in [w*256,+256): 16 L3-direct loads
        const _Float16* AbH = hin_hi + (size_t)(gbase + rowA) * HDIM + w * 256 + lq * 8;
        const _Float16* AbL = hin_lo + (size_t)(gbase + rowA) * HDIM + w * 256 + lq * 8;
        f16x8 ah[8], al[8];
        LOADA(ah, al, AbH, AbL);

        // ---- MFMA: both col-tiles, k-quarter w
        f32x4 a0c0 = {0.f,0.f,0.f,0.f}, a1c0 = {0.f,0.f,0.f,0.f};
        f32x4 a0c1 = {0.f,0.f,0.f,0.f}, a1c1 = {0.f,0.f,0.f,0.f};
        #pragma unroll
        for (int mi = 0; mi < 8; ++mi) {
            const int m = w * 8 + mi;
            f16x8 b0h = *(const f16x8*)&bls[0][m][0][lane][0];
            f16x8 b0l = *(const f16x8*)&bls[1][m][0][lane][0];
            f16x8 b1h = *(const f16x8*)&bls[0][m][1][lane][0];
            f16x8 b1l = *(const f16x8*)&bls[1][m][1][lane][0];
            a0c0 = __builtin_amdgcn_mfma_f32_16x16x32_f16(ah[mi], b0h, a0c0, 0, 0, 0);
            a1c0 = __builtin_amdgcn_mfma_f32_16x16x32_f16(al[mi], b0h, a1c0, 0, 0, 0);
            a1c0 = __builtin_amdgcn_mfma_f32_16x16x32_f16(ah[mi], b0l, a1c0, 0, 0, 0);
            a0c1 = __builtin_amdgcn_mfma_f32_16x16x32_f16(ah[mi], b1h, a0c1, 0, 0, 0);
            a1c1 = __builtin_amdgcn_mfma_f32_16x16x32_f16(al[mi], b1h, a1c1, 0, 0, 0);
            a1c1 = __builtin_amdgcn_mfma_f32_16x16x32_f16(ah[mi], b1l, a1c1, 0, 0, 0);
        }
        f32x4 p0, p1;
        #pragma unroll
        for (int r = 0; r < 4; ++r) {
            p0[r] = a0c0[r] + a1c0[r] * LOINV;
            p1[r] = a0c1[r] + a1c1[r] * LOINV;
        }
        red[par][w][0][lane] = p0;
        red[par][w][1][lane] = p1;
        __syncthreads();   // the ONLY per-step barrier

        // ---- epilogue: thread -> (erow, ecol); sum 4 k-quarter partials
        float s = ((const float*)&red[par][0][ctE][laneE])[rE]
                + ((const float*)&red[par][1][ctE][laneE])[rE]
                + ((const float*)&red[par][2][ctE][laneE])[rE]
                + ((const float*)&red[par][3][ctE][laneE])[rE];
        float pre = s + ev;
        float hv  = tanhf(pre);
        _Float16 h16 = (_Float16)hv;
        _Float16 l16 = (_Float16)((hv - (float)h16) * LOSCALE);

        z[(size_t)(t - t0) * HPLANE + (size_t)gn * HDIM + jcol] = h16;  // cached
        if (t == TSEQ - 1) hlast_out[(size_t)gn * HDIM + jcol] = hv;    // cached

        {   // h exchange: sc0 sc1 -> L3 coherence point; drain via vmcnt(0)
            union { _Float16 f; unsigned short u; } uh{h16}, ul{l16};
            unsigned vh = uh.u, vl = ul.u;
            const _Float16* ph = hout_hi + (size_t)gn * HDIM + jcol;
            const _Float16* pl = hout_lo + (size_t)gn * HDIM + jcol;
            asm volatile("global_store_short %0, %2, off sc0 sc1\n\t"
                         "global_store_short %1, %3, off sc0 sc1\n\t"
                         "s_waitcnt vmcnt(0)"
                         :: "v"(ph), "v"(pl), "v"(vh), "v"(vl) : "memory");
        }
        // per-wave release: all lanes of this wave have drained (lockstep),
        // so lane 0's atomicAdd can't be observed before the wave's h data.
        if ((tid & 63) == 0)
            __hip_atomic_fetch_add(flags + (size_t)t * 32 + xcd * 4 + myq, 1u,
                                   __ATOMIC_RELAXED, __HIP_MEMORY_SCOPE_AGENT);
        tokv = tok_n; ev = e_n;
    }
}

// ---------------------------------------------------------------- output GEMM + softmax
__global__ __launch_bounds__(256, 1) void rnn_out(
    const _Float16* __restrict__ z,      // chunk: [tc][NSEQ*HDIM]
    const _Float16* __restrict__ woutT,  // [ODIM][HDIM]
    const float* __restrict__ bout,      // [ODIM]
    float* __restrict__ y,               // [NSEQ][TSEQ][ODIM]
    int t0, int tc)
{
    const int b = blockIdx.x;
    const int t_rel = b >> 2, ng = b & 3;
    const int t = t0 + t_rel;
    const int n0 = ng * 16;
    const int tid = threadIdx.x;
    const int lane = tid & 63, wv = tid >> 6;
    const int lr = lane & 15, lq = lane >> 4;

    __shared__ float lg[16][ODIM + 8];   // logits staging

    const _Float16* abase = z + (size_t)t_rel * (NSEQ * HDIM)
                              + (size_t)(n0 + lr) * HDIM + lq * 8;
    f16x8 af[32];
    #pragma unroll
    for (int m = 0; m < 32; ++m) af[m] = *(const f16x8*)(abase + m * 32);

    #pragma unroll
    for (int i = 0; i < 4; ++i) {
        int ot = (wv * 4 + i) * 16;
        const _Float16* bbase = woutT + (size_t)(ot + lr) * HDIM + lq * 8;
        f32x4 acc = {0.f, 0.f, 0.f, 0.f};
        #pragma unroll
        for (int m = 0; m < 32; ++m) {
            f16x8 bfr = *(const f16x8*)(bbase + m * 32);
            acc = __builtin_amdgcn_mfma_f32_16x16x32_f16(af[m], bfr, acc, 0, 0, 0);
        }
        #pragma unroll
        for (int r = 0; r < 4; ++r)
            lg[lq * 4 + r][ot + lr] = acc[r];
    }
    __syncthreads();

    for (int rr = 0; rr < 4; ++rr) {
        int row = wv * 4 + rr;
        int n = n0 + row;
        float v0 = lg[row][lane]       + bout[lane];
        float v1 = lg[row][64 + lane]  + bout[64 + lane];
        float v2 = lg[row][128 + lane] + bout[128 + lane];
        float v3 = lg[row][192 + lane] + bout[192 + lane];
        float mx = fmaxf(fmaxf(v0, v1), fmaxf(v2, v3));
        for (int s = 32; s > 0; s >>= 1) mx = fmaxf(mx, __shfl_xor(mx, s));
        float e0 = __expf(v0 - mx), e1 = __expf(v1 - mx);
        float e2v = __expf(v2 - mx), e3 = __expf(v3 - mx);
        float sm = e0 + e1 + e2v + e3;
        for (int s = 32; s > 0; s >>= 1) sm += __shfl_xor(sm, s);
        float inv = 1.f / sm;
        float* dst = y + ((size_t)n * TSEQ + t) * ODIM;
        dst[lane]       = e0 * inv;
        dst[64 + lane]  = e1 * inv;
        dst[128 + lane] = e2v * inv;
        dst[192 + lane] = e3 * inv;
    }
}

// ---------------------------------------------------------------- launch
extern "C" void kernel_launch(void* const* d_in, const int* in_sizes, int n_in,
                              void* d_out, int out_size, void* d_ws, size_t ws_size,
                              hipStream_t stream)
{
    const int*   x    = (const int*)  d_in[0];
    const float* E    = (const float*)d_in[1];
    const float* Whh  = (const float*)d_in[2];
    const float* bh   = (const float*)d_in[3];
    const float* Wout = (const float*)d_in[4];
    const float* bout = (const float*)d_in[5];

    float* y     = (float*)d_out;
    float* hlast = y + (size_t)NSEQ * TSEQ * ODIM;

    char* ws = (char*)d_ws;
    size_t off = 0;
    auto alloc = [&](size_t bytes) -> void* {
        void* p = ws + off;
        off = (off + bytes + 255) & ~(size_t)255;
        return p;
    };
    _Float16* whhT_hi = (_Float16*)alloc((size_t)HDIM * HDIM * 2);
    _Float16* whhT_lo = (_Float16*)alloc((size_t)HDIM * HDIM * 2);
    _Float16* woutT   = (_Float16*)alloc((size_t)ODIM * HDIM * 2);
    float*    e2      = (float*)   alloc((size_t)VOCABSZ * HDIM * 4);
    _Float16* hbuf    = (_Float16*)alloc((size_t)2 * HBUFSZ * 2);
    unsigned* flags   = (unsigned*)alloc((size_t)TSEQ * 32 * 4);
    unsigned* claims  = (unsigned*)alloc((size_t)64 * 8 * 4);
    _Float16* z       = (_Float16*)(ws + off);

    size_t zcap = (ws_size > off) ? (ws_size - off) : 0;
    int tc_max = (int)(zcap / ((size_t)NSEQ * HDIM * 2));
    if (tc_max > TSEQ) tc_max = TSEQ;
    if (tc_max < 1)    tc_max = 1;

    rnn_init<<<2048, 256, 0, stream>>>(Whh, Wout, E, bh, whhT_hi, whhT_lo,
                                       woutT, e2, hbuf, flags, claims);

    int chunk = 0;
    for (int t0 = 0; t0 < TSEQ; t0 += tc_max, ++chunk) {
        int tc = TSEQ - t0 < tc_max ? TSEQ - t0 : tc_max;
        rnn_steps<<<1024, 256, 0, stream>>>(x, e2, whhT_hi, whhT_lo, hbuf,
                                            flags, claims + (chunk & 63) * 8,
                                            z, hlast, t0, t0 + tc);
        rnn_out<<<tc * 4, 256, 0, stream>>>(z, woutT, bout, y, t0, tc);
    }
}

// Round 17
// 5733.941 us; speedup vs baseline: 2.3681x; 1.0006x over previous
//
#include <hip/hip_runtime.h>

// RNN: h_t = tanh(E[x_t] + h_{t-1} @ Whh + bh), T=1024, N=64, H=1024.
// y = softmax(z @ Wout + bout). Output: y (64*1024*256 f32) then h_last (64*1024 f32).
//
// Double-FP16 recurrence (hi + 2^-11*lo of h and Whh) -> fp32-equivalent
// per-step precision (R3..R16: passed, absmax 9.8e-4).
//
// Protocol law (R10/R12/R13 evidence):
//  - h DATA: sc0 sc1 stores/loads (L3 coherence point) + vmcnt(0) drain.
//  - SYNC: atomics only (relaxed, agent scope). R13's sc0 flag/poll HUNG.
//
// R17 = R16 + BUSY-POLL (single variable). R16 counters: MfmaUtil 5.4%,
// VALUBusy 3%, HBM 1.2% -- chip nearly idle -> DVFS won't boost; measured
// 5.3us/step at ~1GHz equals the ~5-6k cycle chain model. Replace s_sleep
// in the poll loop with a register-only FMA burn (4 indep chains x 16) to
// keep the SIMD busy during waits (1 WG/CU -> nothing to starve) and give
// the clock governor a reason to boost.

typedef _Float16 f16x8 __attribute__((ext_vector_type(8)));
typedef float    f32x4 __attribute__((ext_vector_type(4)));

#define NSEQ  64
#define TSEQ  1024
#define HDIM  1024
#define VOCABSZ 256
#define ODIM  256
#define LOSCALE 2048.0f
#define LOINV  (1.0f/2048.0f)

// hbuf layout: [buf(2)][plane(2: hi,lo)][NSEQ][HDIM] fp16
#define HPLANE (NSEQ * HDIM)
#define HBUFSZ (2 * HPLANE)

// ---------------------------------------------------------------- init / prep
__global__ __launch_bounds__(256) void rnn_init(
    const float* __restrict__ Whh, const float* __restrict__ Wout,
    const float* __restrict__ E,   const float* __restrict__ bh,
    _Float16* __restrict__ whhT_hi, _Float16* __restrict__ whhT_lo,
    _Float16* __restrict__ woutT,  float* __restrict__ e2,
    _Float16* __restrict__ hbuf, unsigned* __restrict__ flags,
    unsigned* __restrict__ claims)
{
    int i = blockIdx.x * 256 + threadIdx.x;
    int stride = gridDim.x * 256;
    for (int idx = i; idx < HDIM * HDIM; idx += stride) {
        int j = idx >> 10, k = idx & 1023;
        float w = Whh[k * HDIM + j];
        _Float16 hi = (_Float16)w;
        whhT_hi[idx] = hi;
        whhT_lo[idx] = (_Float16)((w - (float)hi) * LOSCALE);
    }
    for (int idx = i; idx < ODIM * HDIM; idx += stride) {
        int o = idx >> 10, k = idx & 1023;
        woutT[idx] = (_Float16)Wout[k * ODIM + o];
    }
    for (int idx = i; idx < VOCABSZ * HDIM; idx += stride) {
        int j = idx & 1023;
        e2[idx] = E[idx] + bh[j];
    }
    for (int idx = i; idx < 2 * HBUFSZ; idx += stride) hbuf[idx] = (_Float16)0.f;
    for (int idx = i; idx < TSEQ * 32; idx += stride) flags[idx] = 0u;
    for (int idx = i; idx < 64 * 8; idx += stride) claims[idx] = 0u;
}

// ---------------------------------------------------------------- recurrence
// 16 L3-direct loads (sc0 sc1, 16B each, stride 64B) + single vmcnt drain.
// EARLY-CLOBBER outputs (written while [bh]/[bl] still live).
#define LOADA(AH, AL, BH_, BL_)                                              \
    asm volatile(                                                            \
        "global_load_dwordx4 %[o0], %[bh], off sc0 sc1\n\t"                  \
        "global_load_dwordx4 %[o1], %[bh], off offset:64 sc0 sc1\n\t"        \
        "global_load_dwordx4 %[o2], %[bh], off offset:128 sc0 sc1\n\t"       \
        "global_load_dwordx4 %[o3], %[bh], off offset:192 sc0 sc1\n\t"       \
        "global_load_dwordx4 %[o4], %[bh], off offset:256 sc0 sc1\n\t"       \
        "global_load_dwordx4 %[o5], %[bh], off offset:320 sc0 sc1\n\t"       \
        "global_load_dwordx4 %[o6], %[bh], off offset:384 sc0 sc1\n\t"       \
        "global_load_dwordx4 %[o7], %[bh], off offset:448 sc0 sc1\n\t"       \
        "global_load_dwordx4 %[p0], %[bl], off sc0 sc1\n\t"                  \
        "global_load_dwordx4 %[p1], %[bl], off offset:64 sc0 sc1\n\t"        \
        "global_load_dwordx4 %[p2], %[bl], off offset:128 sc0 sc1\n\t"       \
        "global_load_dwordx4 %[p3], %[bl], off offset:192 sc0 sc1\n\t"       \
        "global_load_dwordx4 %[p4], %[bl], off offset:256 sc0 sc1\n\t"       \
        "global_load_dwordx4 %[p5], %[bl], off offset:320 sc0 sc1\n\t"       \
        "global_load_dwordx4 %[p6], %[bl], off offset:384 sc0 sc1\n\t"       \
        "global_load_dwordx4 %[p7], %[bl], off offset:448 sc0 sc1\n\t"       \
        "s_waitcnt vmcnt(0)"                                                 \
        : [o0]"=&v"(AH[0]), [o1]"=&v"(AH[1]), [o2]"=&v"(AH[2]),              \
          [o3]"=&v"(AH[3]), [o4]"=&v"(AH[4]), [o5]"=&v"(AH[5]),              \
          [o6]"=&v"(AH[6]), [o7]"=&v"(AH[7]),                                \
          [p0]"=&v"(AL[0]), [p1]"=&v"(AL[1]), [p2]"=&v"(AL[2]),              \
          [p3]"=&v"(AL[3]), [p4]"=&v"(AL[4]), [p5]"=&v"(AL[5]),              \
          [p6]"=&v"(AL[6]), [p7]"=&v"(AL[7])                                 \
        : [bh]"v"(BH_), [bl]"v"(BL_) : "memory")

__global__ __launch_bounds__(256, 1) void rnn_steps(
    const int*   __restrict__ x,          // [NSEQ][TSEQ]
    const float* __restrict__ e2,         // [VOCAB][HDIM]  (E + bh)
    const _Float16* __restrict__ whhT_hi, // [HDIM][HDIM] j-major
    const _Float16* __restrict__ whhT_lo,
    _Float16* __restrict__ hbuf,
    unsigned* __restrict__ flags,         // [TSEQ][8 xcd][4 quarter] counters
    unsigned* __restrict__ claims,        // [8] for this chunk
    _Float16* __restrict__ z,             // chunk: [tc][NSEQ*HDIM]
    float* __restrict__ hlast_out,        // [NSEQ*HDIM]
    int t0, int t1)
{
    const int tid  = threadIdx.x;
    const int lane = tid & 63;
    const int w    = tid >> 6;         // wave 0..3 = k-quarter
    const int lq   = lane >> 4;        // k sub-chunk 0..3

    __shared__ _Float16 bls[2][32][2][64][8];  // 128 KB Whh^T frags hi/lo
    __shared__ f32x4    red[2][4][2][64];      //  16 KB partials, dbuf by parity
    __shared__ int      slot_s;
    __shared__ unsigned xcd_s;

    // ---- claim a worker slot on this physical XCD
    if (tid == 0) {
        unsigned xcd;
        asm volatile("s_getreg_b32 %0, hwreg(HW_REG_XCC_ID)" : "=s"(xcd));
        xcd &= 7;
        xcd_s  = xcd;
        slot_s = (int)atomicAdd(&claims[xcd], 1u);
    }
    __syncthreads();
    const int slot = slot_s;
    if (slot >= 32) return;            // surplus block
    const unsigned xcd = xcd_s;
    const int gbase = (int)xcd * 8;    // this XCD's 8 sequences
    const int j0c   = slot * 32;       // this WG's 32 columns
    const int myq   = slot >> 3;       // quarter this WG's columns fall in

    // ---- one-time: stage B fragments (32 cols, hi+lo) into LDS
    for (int idx = tid; idx < 8192; idx += 256) {
        int l   = idx & 63;
        int ct_ = (idx >> 6) & 1;
        int m   = (idx >> 7) & 31;
        int pl_ = idx >> 12;
        int col = j0c + ct_ * 16 + (l & 15);
        int k   = m * 32 + (l >> 4) * 8;
        const _Float16* s = (pl_ ? whhT_lo : whhT_hi) + (size_t)col * HDIM + k;
        *(f16x8*)&bls[pl_][m][ct_][l][0] = *(const f16x8*)s;
    }
    __syncthreads();

    const int rowA = lane & 7;

    // epilogue role: one output value per thread
    const int erow = tid >> 5;         // 0..7
    const int ecol = tid & 31;         // 0..31
    const int gn   = gbase + erow;
    const int jcol = j0c + ecol;
    const int ctE  = ecol >> 4;
    const int laneE= ((erow >> 2) << 4) | (ecol & 15);
    const int rE   = erow & 3;

    int   tokv = x[(size_t)gn * TSEQ + t0];
    float ev   = e2[(size_t)tokv * HDIM + jcol];

    for (int t = t0; t < t1; ++t) {
        const int par = t & 1;
        // prefetch next step's token + E value (read-only, cached)
        int tn = (t + 1 < TSEQ) ? t + 1 : TSEQ - 1;
        int tok_n = x[(size_t)gn * TSEQ + tn];
        float e_n = e2[(size_t)tok_n * HDIM + jcol];

        if (t > 0) {
            // wave w needs quarter w of step t-1: poll ONE counter to 32.
            // BUSY-POLL: register-only FMA burn between polls (keeps the
            // SIMD busy -> clock governor boosts; 1 WG/CU so no starvation).
            unsigned* cp = flags + (size_t)(t - 1) * 32 + xcd * 4 + w;
            float b0 = 1.0f + (float)(lane & 7) * 1e-7f;
            float b1 = b0 + 0.25f, b2 = b0 + 0.5f, b3 = b0 + 0.75f;
            while (__hip_atomic_load(cp, __ATOMIC_RELAXED,
                                     __HIP_MEMORY_SCOPE_AGENT) < 32u) {
                #pragma unroll
                for (int i = 0; i < 16; ++i) {
                    b0 = __builtin_fmaf(b0, 1.0000001f, 1e-9f);
                    b1 = __builtin_fmaf(b1, 1.0000001f, 1e-9f);
                    b2 = __builtin_fmaf(b2, 1.0000001f, 1e-9f);
                    b3 = __builtin_fmaf(b3, 1.0000001f, 1e-9f);
                }
                asm volatile("" :: "v"(b0), "v"(b1), "v"(b2), "v"(b3));
            }
        }
        const _Float16* hin_hi  = hbuf + (size_t)( t      & 1) * HBUFSZ;
        const _Float16* hin_lo  = hin_hi + HPLANE;
        _Float16*       hout_hi = hbuf + (size_t)((t + 1) & 1) * HBUFSZ;
        _Float16*       hout_lo = hout_hi + HPLANE;

        // ---- A loads: wave w covers k in [w*256,+256): 16 L3-direct loads
        const _Float16* AbH = hin_hi + (size_t)(gbase + rowA) * HDIM + w * 256 + lq * 8;
        const _Float16* AbL = hin_lo + (size_t)(gbase + rowA) * HDIM + w * 256 + lq * 8;
        f16x8 ah[8], al[8];
        LOADA(ah, al, AbH, AbL);

        // ---- MFMA: both col-tiles, k-quarter w
        f32x4 a0c0 = {0.f,0.f,0.f,0.f}, a1c0 = {0.f,0.f,0.f,0.f};
        f32x4 a0c1 = {0.f,0.f,0.f,0.f}, a1c1 = {0.f,0.f,0.f,0.f};
        #pragma unroll
        for (int mi = 0; mi < 8; ++mi) {
            const int m = w * 8 + mi;
            f16x8 b0h = *(const f16x8*)&bls[0][m][0][lane][0];
            f16x8 b0l = *(const f16x8*)&bls[1][m][0][lane][0];
            f16x8 b1h = *(const f16x8*)&bls[0][m][1][lane][0];
            f16x8 b1l = *(const f16x8*)&bls[1][m][1][lane][0];
            a0c0 = __builtin_amdgcn_mfma_f32_16x16x32_f16(ah[mi], b0h, a0c0, 0, 0, 0);
            a1c0 = __builtin_amdgcn_mfma_f32_16x16x32_f16(al[mi], b0h, a1c0, 0, 0, 0);
            a1c0 = __builtin_amdgcn_mfma_f32_16x16x32_f16(ah[mi], b0l, a1c0, 0, 0, 0);
            a0c1 = __builtin_amdgcn_mfma_f32_16x16x32_f16(ah[mi], b1h, a0c1, 0, 0, 0);
            a1c1 = __builtin_amdgcn_mfma_f32_16x16x32_f16(al[mi], b1h, a1c1, 0, 0, 0);
            a1c1 = __builtin_amdgcn_mfma_f32_16x16x32_f16(ah[mi], b1l, a1c1, 0, 0, 0);
        }
        f32x4 p0, p1;
        #pragma unroll
        for (int r = 0; r < 4; ++r) {
            p0[r] = a0c0[r] + a1c0[r] * LOINV;
            p1[r] = a0c1[r] + a1c1[r] * LOINV;
        }
        red[par][w][0][lane] = p0;
        red[par][w][1][lane] = p1;
        __syncthreads();   // the ONLY per-step barrier

        // ---- epilogue: thread -> (erow, ecol); sum 4 k-quarter partials
        float s = ((const float*)&red[par][0][ctE][laneE])[rE]
                + ((const float*)&red[par][1][ctE][laneE])[rE]
                + ((const float*)&red[par][2][ctE][laneE])[rE]
                + ((const float*)&red[par][3][ctE][laneE])[rE];
        float pre = s + ev;
        float hv  = tanhf(pre);
        _Float16 h16 = (_Float16)hv;
        _Float16 l16 = (_Float16)((hv - (float)h16) * LOSCALE);

        z[(size_t)(t - t0) * HPLANE + (size_t)gn * HDIM + jcol] = h16;  // cached
        if (t == TSEQ - 1) hlast_out[(size_t)gn * HDIM + jcol] = hv;    // cached

        {   // h exchange: sc0 sc1 -> L3 coherence point; drain via vmcnt(0)
            union { _Float16 f; unsigned short u; } uh{h16}, ul{l16};
            unsigned vh = uh.u, vl = ul.u;
            const _Float16* ph = hout_hi + (size_t)gn * HDIM + jcol;
            const _Float16* pl = hout_lo + (size_t)gn * HDIM + jcol;
            asm volatile("global_store_short %0, %2, off sc0 sc1\n\t"
                         "global_store_short %1, %3, off sc0 sc1\n\t"
                         "s_waitcnt vmcnt(0)"
                         :: "v"(ph), "v"(pl), "v"(vh), "v"(vl) : "memory");
        }
        // per-wave release: all lanes of this wave have drained (lockstep),
        // so lane 0's atomicAdd can't be observed before the wave's h data.
        if ((tid & 63) == 0)
            __hip_atomic_fetch_add(flags + (size_t)t * 32 + xcd * 4 + myq, 1u,
                                   __ATOMIC_RELAXED, __HIP_MEMORY_SCOPE_AGENT);
        tokv = tok_n; ev = e_n;
    }
}

// ---------------------------------------------------------------- output GEMM + softmax
__global__ __launch_bounds__(256, 1) void rnn_out(
    const _Float16* __restrict__ z,      // chunk: [tc][NSEQ*HDIM]
    const _Float16* __restrict__ woutT,  // [ODIM][HDIM]
    const float* __restrict__ bout,      // [ODIM]
    float* __restrict__ y,               // [NSEQ][TSEQ][ODIM]
    int t0, int tc)
{
    const int b = blockIdx.x;
    const int t_rel = b >> 2, ng = b & 3;
    const int t = t0 + t_rel;
    const int n0 = ng * 16;
    const int tid = threadIdx.x;
    const int lane = tid & 63, wv = tid >> 6;
    const int lr = lane & 15, lq = lane >> 4;

    __shared__ float lg[16][ODIM + 8];   // logits staging

    const _Float16* abase = z + (size_t)t_rel * (NSEQ * HDIM)
                              + (size_t)(n0 + lr) * HDIM + lq * 8;
    f16x8 af[32];
    #pragma unroll
    for (int m = 0; m < 32; ++m) af[m] = *(const f16x8*)(abase + m * 32);

    #pragma unroll
    for (int i = 0; i < 4; ++i) {
        int ot = (wv * 4 + i) * 16;
        const _Float16* bbase = woutT + (size_t)(ot + lr) * HDIM + lq * 8;
        f32x4 acc = {0.f, 0.f, 0.f, 0.f};
        #pragma unroll
        for (int m = 0; m < 32; ++m) {
            f16x8 bfr = *(const f16x8*)(bbase + m * 32);
            acc = __builtin_amdgcn_mfma_f32_16x16x32_f16(af[m], bfr, acc, 0, 0, 0);
        }
        #pragma unroll
        for (int r = 0; r < 4; ++r)
            lg[lq * 4 + r][ot + lr] = acc[r];
    }
    __syncthreads();

    for (int rr = 0; rr < 4; ++rr) {
        int row = wv * 4 + rr;
        int n = n0 + row;
        float v0 = lg[row][lane]       + bout[lane];
        float v1 = lg[row][64 + lane]  + bout[64 + lane];
        float v2 = lg[row][128 + lane] + bout[128 + lane];
        float v3 = lg[row][192 + lane] + bout[192 + lane];
        float mx = fmaxf(fmaxf(v0, v1), fmaxf(v2, v3));
        for (int s = 32; s > 0; s >>= 1) mx = fmaxf(mx, __shfl_xor(mx, s));
        float e0 = __expf(v0 - mx), e1 = __expf(v1 - mx);
        float e2v = __expf(v2 - mx), e3 = __expf(v3 - mx);
        float sm = e0 + e1 + e2v + e3;
        for (int s = 32; s > 0; s >>= 1) sm += __shfl_xor(sm, s);
        float inv = 1.f / sm;
        float* dst = y + ((size_t)n * TSEQ + t) * ODIM;
        dst[lane]       = e0 * inv;
        dst[64 + lane]  = e1 * inv;
        dst[128 + lane] = e2v * inv;
        dst[192 + lane] = e3 * inv;
    }
}

// ---------------------------------------------------------------- launch
extern "C" void kernel_launch(void* const* d_in, const int* in_sizes, int n_in,
                              void* d_out, int out_size, void* d_ws, size_t ws_size,
                              hipStream_t stream)
{
    const int*   x    = (const int*)  d_in[0];
    const float* E    = (const float*)d_in[1];
    const float* Whh  = (const float*)d_in[2];
    const float* bh   = (const float*)d_in[3];
    const float* Wout = (const float*)d_in[4];
    const float* bout = (const float*)d_in[5];

    float* y     = (float*)d_out;
    float* hlast = y + (size_t)NSEQ * TSEQ * ODIM;

    char* ws = (char*)d_ws;
    size_t off = 0;
    auto alloc = [&](size_t bytes) -> void* {
        void* p = ws + off;
        off = (off + bytes + 255) & ~(size_t)255;
        return p;
    };
    _Float16* whhT_hi = (_Float16*)alloc((size_t)HDIM * HDIM * 2);
    _Float16* whhT_lo = (_Float16*)alloc((size_t)HDIM * HDIM * 2);
    _Float16* woutT   = (_Float16*)alloc((size_t)ODIM * HDIM * 2);
    float*    e2      = (float*)   alloc((size_t)VOCABSZ * HDIM * 4);
    _Float16* hbuf    = (_Float16*)alloc((size_t)2 * HBUFSZ * 2);
    unsigned* flags   = (unsigned*)alloc((size_t)TSEQ * 32 * 4);
    unsigned* claims  = (unsigned*)alloc((size_t)64 * 8 * 4);
    _Float16* z       = (_Float16*)(ws + off);

    size_t zcap = (ws_size > off) ? (ws_size - off) : 0;
    int tc_max = (int)(zcap / ((size_t)NSEQ * HDIM * 2));
    if (tc_max > TSEQ) tc_max = TSEQ;
    if (tc_max < 1)    tc_max = 1;

    rnn_init<<<2048, 256, 0, stream>>>(Whh, Wout, E, bh, whhT_hi, whhT_lo,
                                       woutT, e2, hbuf, flags, claims);

    int chunk = 0;
    for (int t0 = 0; t0 < TSEQ; t0 += tc_max, ++chunk) {
        int tc = TSEQ - t0 < tc_max ? TSEQ - t0 : tc_max;
        rnn_steps<<<1024, 256, 0, stream>>>(x, e2, whhT_hi, whhT_lo, hbuf,
                                            flags, claims + (chunk & 63) * 8,
                                            z, hlast, t0, t0 + tc);
        rnn_out<<<tc * 4, 256, 0, stream>>>(z, woutT, bout, y, t0, tc);
    }
}

// Round 18
// 4371.622 us; speedup vs baseline: 3.1060x; 1.3116x over previous
//
#include <hip/hip_runtime.h>

// RNN: h_t = tanh(E[x_t] + h_{t-1} @ Whh + bh), T=1024, N=64, H=1024.
// y = softmax(z @ Wout + bout). Output: y (64*1024*256 f32) then h_last (64*1024 f32).
//
// Double-FP16 recurrence (hi + 2^-11*lo of h and Whh) -> fp32-equivalent
// per-step precision (R3..R17: passed, absmax 9.8e-4).
//
// Protocol law (R10/R12/R13 evidence):
//  - h DATA: sc0 sc1 stores/loads (L3 coherence point) + vmcnt(0) drain.
//  - SYNC: agent atomics only. R13's plain-sc0 flag/poll HUNG.
//
// R18 = R16 + (1) PARALLEL FLAG ARRAY: R16's per-quarter counter required 32
// relaxed atomicAdds to ONE dword per step -- RMWs serialize at the L3 bank
// (~600-1000cy serial tail). Now each wave atomic-STOREs its own dword
// flags[t][xcd][q][(slot&7)*4+w] (parallel); consumer polls the 32-dword
// line coalesced (R12-proven mechanism, finer grain). (2) z/hlast stores
// moved AFTER the flag post -- off the h-drain's vmcnt(0) critical path.
// R17's FMA busy-poll reverted (proven null: VALUBusy 3.0->3.1%).

typedef _Float16 f16x8 __attribute__((ext_vector_type(8)));
typedef float    f32x4 __attribute__((ext_vector_type(4)));

#define NSEQ  64
#define TSEQ  1024
#define HDIM  1024
#define VOCABSZ 256
#define ODIM  256
#define LOSCALE 2048.0f
#define LOINV  (1.0f/2048.0f)

// hbuf layout: [buf(2)][plane(2: hi,lo)][NSEQ][HDIM] fp16
#define HPLANE (NSEQ * HDIM)
#define HBUFSZ (2 * HPLANE)
// flags layout: [TSEQ][8 xcd][4 quarter][32 entity] u32
#define FSTEP 1024

// ---------------------------------------------------------------- init / prep
__global__ __launch_bounds__(256) void rnn_init(
    const float* __restrict__ Whh, const float* __restrict__ Wout,
    const float* __restrict__ E,   const float* __restrict__ bh,
    _Float16* __restrict__ whhT_hi, _Float16* __restrict__ whhT_lo,
    _Float16* __restrict__ woutT,  float* __restrict__ e2,
    _Float16* __restrict__ hbuf, unsigned* __restrict__ flags,
    unsigned* __restrict__ claims)
{
    int i = blockIdx.x * 256 + threadIdx.x;
    int stride = gridDim.x * 256;
    for (int idx = i; idx < HDIM * HDIM; idx += stride) {
        int j = idx >> 10, k = idx & 1023;
        float w = Whh[k * HDIM + j];
        _Float16 hi = (_Float16)w;
        whhT_hi[idx] = hi;
        whhT_lo[idx] = (_Float16)((w - (float)hi) * LOSCALE);
    }
    for (int idx = i; idx < ODIM * HDIM; idx += stride) {
        int o = idx >> 10, k = idx & 1023;
        woutT[idx] = (_Float16)Wout[k * ODIM + o];
    }
    for (int idx = i; idx < VOCABSZ * HDIM; idx += stride) {
        int j = idx & 1023;
        e2[idx] = E[idx] + bh[j];
    }
    for (int idx = i; idx < 2 * HBUFSZ; idx += stride) hbuf[idx] = (_Float16)0.f;
    for (size_t idx = i; idx < (size_t)TSEQ * FSTEP; idx += stride) flags[idx] = 0u;
    for (int idx = i; idx < 64 * 8; idx += stride) claims[idx] = 0u;
}

// ---------------------------------------------------------------- recurrence
// 16 L3-direct loads (sc0 sc1, 16B each, stride 64B) + single vmcnt drain.
// EARLY-CLOBBER outputs (written while [bh]/[bl] still live).
#define LOADA(AH, AL, BH_, BL_)                                              \
    asm volatile(                                                            \
        "global_load_dwordx4 %[o0], %[bh], off sc0 sc1\n\t"                  \
        "global_load_dwordx4 %[o1], %[bh], off offset:64 sc0 sc1\n\t"        \
        "global_load_dwordx4 %[o2], %[bh], off offset:128 sc0 sc1\n\t"       \
        "global_load_dwordx4 %[o3], %[bh], off offset:192 sc0 sc1\n\t"       \
        "global_load_dwordx4 %[o4], %[bh], off offset:256 sc0 sc1\n\t"       \
        "global_load_dwordx4 %[o5], %[bh], off offset:320 sc0 sc1\n\t"       \
        "global_load_dwordx4 %[o6], %[bh], off offset:384 sc0 sc1\n\t"       \
        "global_load_dwordx4 %[o7], %[bh], off offset:448 sc0 sc1\n\t"       \
        "global_load_dwordx4 %[p0], %[bl], off sc0 sc1\n\t"                  \
        "global_load_dwordx4 %[p1], %[bl], off offset:64 sc0 sc1\n\t"        \
        "global_load_dwordx4 %[p2], %[bl], off offset:128 sc0 sc1\n\t"       \
        "global_load_dwordx4 %[p3], %[bl], off offset:192 sc0 sc1\n\t"       \
        "global_load_dwordx4 %[p4], %[bl], off offset:256 sc0 sc1\n\t"       \
        "global_load_dwordx4 %[p5], %[bl], off offset:320 sc0 sc1\n\t"       \
        "global_load_dwordx4 %[p6], %[bl], off offset:384 sc0 sc1\n\t"       \
        "global_load_dwordx4 %[p7], %[bl], off offset:448 sc0 sc1\n\t"       \
        "s_waitcnt vmcnt(0)"                                                 \
        : [o0]"=&v"(AH[0]), [o1]"=&v"(AH[1]), [o2]"=&v"(AH[2]),              \
          [o3]"=&v"(AH[3]), [o4]"=&v"(AH[4]), [o5]"=&v"(AH[5]),              \
          [o6]"=&v"(AH[6]), [o7]"=&v"(AH[7]),                                \
          [p0]"=&v"(AL[0]), [p1]"=&v"(AL[1]), [p2]"=&v"(AL[2]),              \
          [p3]"=&v"(AL[3]), [p4]"=&v"(AL[4]), [p5]"=&v"(AL[5]),              \
          [p6]"=&v"(AL[6]), [p7]"=&v"(AL[7])                                 \
        : [bh]"v"(BH_), [bl]"v"(BL_) : "memory")

__global__ __launch_bounds__(256, 1) void rnn_steps(
    const int*   __restrict__ x,          // [NSEQ][TSEQ]
    const float* __restrict__ e2,         // [VOCAB][HDIM]  (E + bh)
    const _Float16* __restrict__ whhT_hi, // [HDIM][HDIM] j-major
    const _Float16* __restrict__ whhT_lo,
    _Float16* __restrict__ hbuf,
    unsigned* __restrict__ flags,         // [TSEQ][8][4][32]
    unsigned* __restrict__ claims,        // [8] for this chunk
    _Float16* __restrict__ z,             // chunk: [tc][NSEQ*HDIM]
    float* __restrict__ hlast_out,        // [NSEQ*HDIM]
    int t0, int t1)
{
    const int tid  = threadIdx.x;
    const int lane = tid & 63;
    const int w    = tid >> 6;         // wave 0..3 = k-quarter
    const int lq   = lane >> 4;        // k sub-chunk 0..3

    __shared__ _Float16 bls[2][32][2][64][8];  // 128 KB Whh^T frags hi/lo
    __shared__ f32x4    red[2][4][2][64];      //  16 KB partials, dbuf by parity
    __shared__ int      slot_s;
    __shared__ unsigned xcd_s;

    // ---- claim a worker slot on this physical XCD
    if (tid == 0) {
        unsigned xcd;
        asm volatile("s_getreg_b32 %0, hwreg(HW_REG_XCC_ID)" : "=s"(xcd));
        xcd &= 7;
        xcd_s  = xcd;
        slot_s = (int)atomicAdd(&claims[xcd], 1u);
    }
    __syncthreads();
    const int slot = slot_s;
    if (slot >= 32) return;            // surplus block
    const unsigned xcd = xcd_s;
    const int gbase = (int)xcd * 8;    // this XCD's 8 sequences
    const int j0c   = slot * 32;       // this WG's 32 columns
    const int myq   = slot >> 3;       // quarter this WG's columns fall in
    const int ent   = (slot & 7) * 4 + w;  // flag entity within quarter

    // ---- one-time: stage B fragments (32 cols, hi+lo) into LDS
    for (int idx = tid; idx < 8192; idx += 256) {
        int l   = idx & 63;
        int ct_ = (idx >> 6) & 1;
        int m   = (idx >> 7) & 31;
        int pl_ = idx >> 12;
        int col = j0c + ct_ * 16 + (l & 15);
        int k   = m * 32 + (l >> 4) * 8;
        const _Float16* s = (pl_ ? whhT_lo : whhT_hi) + (size_t)col * HDIM + k;
        *(f16x8*)&bls[pl_][m][ct_][l][0] = *(const f16x8*)s;
    }
    __syncthreads();

    const int rowA = lane & 7;

    // epilogue role: one output value per thread
    const int erow = tid >> 5;         // 0..7
    const int ecol = tid & 31;         // 0..31
    const int gn   = gbase + erow;
    const int jcol = j0c + ecol;
    const int ctE  = ecol >> 4;
    const int laneE= ((erow >> 2) << 4) | (ecol & 15);
    const int rE   = erow & 3;

    int   tokv = x[(size_t)gn * TSEQ + t0];
    float ev   = e2[(size_t)tokv * HDIM + jcol];

    for (int t = t0; t < t1; ++t) {
        const int par = t & 1;
        // prefetch next step's token + E value (read-only, cached)
        int tn = (t + 1 < TSEQ) ? t + 1 : TSEQ - 1;
        int tok_n = x[(size_t)gn * TSEQ + tn];
        float e_n = e2[(size_t)tok_n * HDIM + jcol];

        if (t > 0) {
            // wave w needs quarter w of step t-1: poll 32 parallel flags
            // (slots 8w..8w+7 x 4 waves), one coalesced 128B L3 load/iter.
            const unsigned* fp = flags + (size_t)(t - 1) * FSTEP + xcd * 128
                               + w * 32 + (lane & 31);
            while (!__all((int)(__hip_atomic_load(fp, __ATOMIC_RELAXED,
                                   __HIP_MEMORY_SCOPE_AGENT) != 0u)))
                __builtin_amdgcn_s_sleep(1);
        }
        const _Float16* hin_hi  = hbuf + (size_t)( t      & 1) * HBUFSZ;
        const _Float16* hin_lo  = hin_hi + HPLANE;
        _Float16*       hout_hi = hbuf + (size_t)((t + 1) & 1) * HBUFSZ;
        _Float16*       hout_lo = hout_hi + HPLANE;

        // ---- A loads: wave w covers k in [w*256,+256): 16 L3-direct loads
        const _Float16* AbH = hin_hi + (size_t)(gbase + rowA) * HDIM + w * 256 + lq * 8;
        const _Float16* AbL = hin_lo + (size_t)(gbase + rowA) * HDIM + w * 256 + lq * 8;
        f16x8 ah[8], al[8];
        LOADA(ah, al, AbH, AbL);

        // ---- MFMA: both col-tiles, k-quarter w
        f32x4 a0c0 = {0.f,0.f,0.f,0.f}, a1c0 = {0.f,0.f,0.f,0.f};
        f32x4 a0c1 = {0.f,0.f,0.f,0.f}, a1c1 = {0.f,0.f,0.f,0.f};
        #pragma unroll
        for (int mi = 0; mi < 8; ++mi) {
            const int m = w * 8 + mi;
            f16x8 b0h = *(const f16x8*)&bls[0][m][0][lane][0];
            f16x8 b0l = *(const f16x8*)&bls[1][m][0][lane][0];
            f16x8 b1h = *(const f16x8*)&bls[0][m][1][lane][0];
            f16x8 b1l = *(const f16x8*)&bls[1][m][1][lane][0];
            a0c0 = __builtin_amdgcn_mfma_f32_16x16x32_f16(ah[mi], b0h, a0c0, 0, 0, 0);
            a1c0 = __builtin_amdgcn_mfma_f32_16x16x32_f16(al[mi], b0h, a1c0, 0, 0, 0);
            a1c0 = __builtin_amdgcn_mfma_f32_16x16x32_f16(ah[mi], b0l, a1c0, 0, 0, 0);
            a0c1 = __builtin_amdgcn_mfma_f32_16x16x32_f16(ah[mi], b1h, a0c1, 0, 0, 0);
            a1c1 = __builtin_amdgcn_mfma_f32_16x16x32_f16(al[mi], b1h, a1c1, 0, 0, 0);
            a1c1 = __builtin_amdgcn_mfma_f32_16x16x32_f16(ah[mi], b1l, a1c1, 0, 0, 0);
        }
        f32x4 p0, p1;
        #pragma unroll
        for (int r = 0; r < 4; ++r) {
            p0[r] = a0c0[r] + a1c0[r] * LOINV;
            p1[r] = a0c1[r] + a1c1[r] * LOINV;
        }
        red[par][w][0][lane] = p0;
        red[par][w][1][lane] = p1;
        __syncthreads();   // the ONLY per-step barrier

        // ---- epilogue: thread -> (erow, ecol); sum 4 k-quarter partials
        float s = ((const float*)&red[par][0][ctE][laneE])[rE]
                + ((const float*)&red[par][1][ctE][laneE])[rE]
                + ((const float*)&red[par][2][ctE][laneE])[rE]
                + ((const float*)&red[par][3][ctE][laneE])[rE];
        float pre = s + ev;
        float hv  = tanhf(pre);
        _Float16 h16 = (_Float16)hv;
        _Float16 l16 = (_Float16)((hv - (float)h16) * LOSCALE);

        {   // h exchange FIRST: sc0 sc1 -> L3 coherence point; vmcnt(0) drain
            union { _Float16 f; unsigned short u; } uh{h16}, ul{l16};
            unsigned vh = uh.u, vl = ul.u;
            const _Float16* ph = hout_hi + (size_t)gn * HDIM + jcol;
            const _Float16* pl = hout_lo + (size_t)gn * HDIM + jcol;
            asm volatile("global_store_short %0, %2, off sc0 sc1\n\t"
                         "global_store_short %1, %3, off sc0 sc1\n\t"
                         "s_waitcnt vmcnt(0)"
                         :: "v"(ph), "v"(pl), "v"(vh), "v"(vl) : "memory");
        }
        // per-wave release: parallel atomic STORE to this wave's own dword
        // (no RMW serialization; R12-proven store->poll mechanism). Lockstep
        // wave => lane 0's store can't precede the wave's drained h.
        if ((tid & 63) == 0)
            __hip_atomic_store(flags + (size_t)t * FSTEP + xcd * 128
                               + myq * 32 + ent, 1u,
                               __ATOMIC_RELAXED, __HIP_MEMORY_SCOPE_AGENT);
        // z / hlast AFTER the release: off the critical path (cached stores
        // complete during the next poll window).
        z[(size_t)(t - t0) * HPLANE + (size_t)gn * HDIM + jcol] = h16;
        if (t == TSEQ - 1) hlast_out[(size_t)gn * HDIM + jcol] = hv;
        tokv = tok_n; ev = e_n;
    }
}

// ---------------------------------------------------------------- output GEMM + softmax
__global__ __launch_bounds__(256, 1) void rnn_out(
    const _Float16* __restrict__ z,      // chunk: [tc][NSEQ*HDIM]
    const _Float16* __restrict__ woutT,  // [ODIM][HDIM]
    const float* __restrict__ bout,      // [ODIM]
    float* __restrict__ y,               // [NSEQ][TSEQ][ODIM]
    int t0, int tc)
{
    const int b = blockIdx.x;
    const int t_rel = b >> 2, ng = b & 3;
    const int t = t0 + t_rel;
    const int n0 = ng * 16;
    const int tid = threadIdx.x;
    const int lane = tid & 63, wv = tid >> 6;
    const int lr = lane & 15, lq = lane >> 4;

    __shared__ float lg[16][ODIM + 8];   // logits staging

    const _Float16* abase = z + (size_t)t_rel * (NSEQ * HDIM)
                              + (size_t)(n0 + lr) * HDIM + lq * 8;
    f16x8 af[32];
    #pragma unroll
    for (int m = 0; m < 32; ++m) af[m] = *(const f16x8*)(abase + m * 32);

    #pragma unroll
    for (int i = 0; i < 4; ++i) {
        int ot = (wv * 4 + i) * 16;
        const _Float16* bbase = woutT + (size_t)(ot + lr) * HDIM + lq * 8;
        f32x4 acc = {0.f, 0.f, 0.f, 0.f};
        #pragma unroll
        for (int m = 0; m < 32; ++m) {
            f16x8 bfr = *(const f16x8*)(bbase + m * 32);
            acc = __builtin_amdgcn_mfma_f32_16x16x32_f16(af[m], bfr, acc, 0, 0, 0);
        }
        #pragma unroll
        for (int r = 0; r < 4; ++r)
            lg[lq * 4 + r][ot + lr] = acc[r];
    }
    __syncthreads();

    for (int rr = 0; rr < 4; ++rr) {
        int row = wv * 4 + rr;
        int n = n0 + row;
        float v0 = lg[row][lane]       + bout[lane];
        float v1 = lg[row][64 + lane]  + bout[64 + lane];
        float v2 = lg[row][128 + lane] + bout[128 + lane];
        float v3 = lg[row][192 + lane] + bout[192 + lane];
        float mx = fmaxf(fmaxf(v0, v1), fmaxf(v2, v3));
        for (int s = 32; s > 0; s >>= 1) mx = fmaxf(mx, __shfl_xor(mx, s));
        float e0 = __expf(v0 - mx), e1 = __expf(v1 - mx);
        float e2v = __expf(v2 - mx), e3 = __expf(v3 - mx);
        float sm = e0 + e1 + e2v + e3;
        for (int s = 32; s > 0; s >>= 1) sm += __shfl_xor(sm, s);
        float inv = 1.f / sm;
        float* dst = y + ((size_t)n * TSEQ + t) * ODIM;
        dst[lane]       = e0 * inv;
        dst[64 + lane]  = e1 * inv;
        dst[128 + lane] = e2v * inv;
        dst[192 + lane] = e3 * inv;
    }
}

// ---------------------------------------------------------------- launch
extern "C" void kernel_launch(void* const* d_in, const int* in_sizes, int n_in,
                              void* d_out, int out_size, void* d_ws, size_t ws_size,
                              hipStream_t stream)
{
    const int*   x    = (const int*)  d_in[0];
    const float* E    = (const float*)d_in[1];
    const float* Whh  = (const float*)d_in[2];
    const float* bh   = (const float*)d_in[3];
    const float* Wout = (const float*)d_in[4];
    const float* bout = (const float*)d_in[5];

    float* y     = (float*)d_out;
    float* hlast = y + (size_t)NSEQ * TSEQ * ODIM;

    char* ws = (char*)d_ws;
    size_t off = 0;
    auto alloc = [&](size_t bytes) -> void* {
        void* p = ws + off;
        off = (off + bytes + 255) & ~(size_t)255;
        return p;
    };
    _Float16* whhT_hi = (_Float16*)alloc((size_t)HDIM * HDIM * 2);
    _Float16* whhT_lo = (_Float16*)alloc((size_t)HDIM * HDIM * 2);
    _Float16* woutT   = (_Float16*)alloc((size_t)ODIM * HDIM * 2);
    float*    e2      = (float*)   alloc((size_t)VOCABSZ * HDIM * 4);
    _Float16* hbuf    = (_Float16*)alloc((size_t)2 * HBUFSZ * 2);
    unsigned* flags   = (unsigned*)alloc((size_t)TSEQ * FSTEP * 4);
    unsigned* claims  = (unsigned*)alloc((size_t)64 * 8 * 4);
    _Float16* z       = (_Float16*)(ws + off);

    size_t zcap = (ws_size > off) ? (ws_size - off) : 0;
    int tc_max = (int)(zcap / ((size_t)NSEQ * HDIM * 2));
    if (tc_max > TSEQ) tc_max = TSEQ;
    if (tc_max < 1)    tc_max = 1;

    rnn_init<<<2048, 256, 0, stream>>>(Whh, Wout, E, bh, whhT_hi, whhT_lo,
                                       woutT, e2, hbuf, flags, claims);

    int chunk = 0;
    for (int t0 = 0; t0 < TSEQ; t0 += tc_max, ++chunk) {
        int tc = TSEQ - t0 < tc_max ? TSEQ - t0 : tc_max;
        rnn_steps<<<1024, 256, 0, stream>>>(x, e2, whhT_hi, whhT_lo, hbuf,
                                            flags, claims + (chunk & 63) * 8,
                                            z, hlast, t0, t0 + tc);
        rnn_out<<<tc * 4, 256, 0, stream>>>(z, woutT, bout, y, t0, tc);
    }
}

// Round 20
// 4195.330 us; speedup vs baseline: 3.2365x; 1.0420x over previous
//
#include <hip/hip_runtime.h>

// RNN: h_t = tanh(E[x_t] + h_{t-1} @ Whh + bh), T=1024, N=64, H=1024.
// y = softmax(z @ Wout + bout). Output: y (64*1024*256 f32) then h_last (64*1024 f32).
//
// Double-FP16 recurrence (hi + 2^-11*lo of h and Whh) -> fp32-equivalent
// per-step precision (R3..R18: passed, absmax 9.8e-4).
//
// Protocol law (R10/R12/R13): cross-WG data via sc0 sc1 (L3 coherence point).
// R19's side-tag scheme FAILED (0.259): seqlock read race -- concurrent
// data+tag loads can see fresh tag with stale data.
//
// R20: PER-DWORD GENERATION BITS (race-free self-certification).
//  - h element = one dword: h16 | l16<<16, with l16's LSB (dword bit 16)
//    REPLACED by generation bit g = ((t+1)>>1)&1 (disambiguates the parity
//    buffer's current vs previous occupant; slot reused every 2 steps).
//  - consumer retries a 16-load L3 burst until ALL 64 loaded dwords carry the
//    expected gen bit (AND/OR tree + __all). The certificate is IN the bytes
//    being consumed -> stale data can never validate. No flags, no tags, no
//    producer drain (fire-and-forget store).
//  - LSB steal perturbs l16 by <=1 ulp -> <=2^-21 relative on h. Negligible.
//  - guard (2^14 retries) -> absmax fail instead of hang on any liveness bug.

typedef _Float16 f16x8 __attribute__((ext_vector_type(8)));
typedef float    f32x4 __attribute__((ext_vector_type(4)));
typedef unsigned u32x4 __attribute__((ext_vector_type(4)));

#define NSEQ  64
#define TSEQ  1024
#define HDIM  1024
#define VOCABSZ 256
#define ODIM  256
#define LOSCALE 2048.0f
#define LOINV  (1.0f/2048.0f)

// hpk layout: [buf(2)][NSEQ][HDIM] u32 (h16 | l16<<16, bit16 = gen)
#define HPLANE (NSEQ * HDIM)

// ---------------------------------------------------------------- init / prep
__global__ __launch_bounds__(256) void rnn_init(
    const float* __restrict__ Whh, const float* __restrict__ Wout,
    const float* __restrict__ E,   const float* __restrict__ bh,
    _Float16* __restrict__ whhT_hi, _Float16* __restrict__ whhT_lo,
    _Float16* __restrict__ woutT,  float* __restrict__ e2,
    unsigned* __restrict__ hpk, unsigned* __restrict__ claims)
{
    int i = blockIdx.x * 256 + threadIdx.x;
    int stride = gridDim.x * 256;
    for (int idx = i; idx < HDIM * HDIM; idx += stride) {
        int j = idx >> 10, k = idx & 1023;
        float w = Whh[k * HDIM + j];
        _Float16 hi = (_Float16)w;
        whhT_hi[idx] = hi;
        whhT_lo[idx] = (_Float16)((w - (float)hi) * LOSCALE);
    }
    for (int idx = i; idx < ODIM * HDIM; idx += stride) {
        int o = idx >> 10, k = idx & 1023;
        woutT[idx] = (_Float16)Wout[k * ODIM + o];
    }
    for (int idx = i; idx < VOCABSZ * HDIM; idx += stride) {
        int j = idx & 1023;
        e2[idx] = E[idx] + bh[j];
    }
    // h0 = 0, gen bit 0 (t=0 expects g=(0>>1)&1=0; buffer1's first writer is
    // step 0 with g=((0+1)>>1)&1=0 -> init buffer1 bit16=0 is never consumed
    // before being overwritten, but zero it anyway).
    for (int idx = i; idx < 2 * HPLANE; idx += stride) hpk[idx] = 0u;
    for (int idx = i; idx < 64 * 8; idx += stride) claims[idx] = 0u;
}

// ---------------------------------------------------------------- recurrence
// One burst: 16 packed-data loads (16B each), L3-direct (sc0 sc1), single
// vmcnt(0). Early-clobber outputs.
#define LOADPK(P, PKB)                                                       \
    asm volatile(                                                            \
        "global_load_dwordx4 %[q0], %[pb], off sc0 sc1\n\t"                  \
        "global_load_dwordx4 %[q1], %[pb], off offset:16 sc0 sc1\n\t"        \
        "global_load_dwordx4 %[q2], %[pb], off offset:128 sc0 sc1\n\t"       \
        "global_load_dwordx4 %[q3], %[pb], off offset:144 sc0 sc1\n\t"       \
        "global_load_dwordx4 %[q4], %[pb], off offset:256 sc0 sc1\n\t"       \
        "global_load_dwordx4 %[q5], %[pb], off offset:272 sc0 sc1\n\t"       \
        "global_load_dwordx4 %[q6], %[pb], off offset:384 sc0 sc1\n\t"       \
        "global_load_dwordx4 %[q7], %[pb], off offset:400 sc0 sc1\n\t"       \
        "global_load_dwordx4 %[q8], %[pb], off offset:512 sc0 sc1\n\t"       \
        "global_load_dwordx4 %[q9], %[pb], off offset:528 sc0 sc1\n\t"       \
        "global_load_dwordx4 %[qa], %[pb], off offset:640 sc0 sc1\n\t"       \
        "global_load_dwordx4 %[qb], %[pb], off offset:656 sc0 sc1\n\t"       \
        "global_load_dwordx4 %[qc], %[pb], off offset:768 sc0 sc1\n\t"       \
        "global_load_dwordx4 %[qd], %[pb], off offset:784 sc0 sc1\n\t"       \
        "global_load_dwordx4 %[qe], %[pb], off offset:896 sc0 sc1\n\t"       \
        "global_load_dwordx4 %[qf], %[pb], off offset:912 sc0 sc1\n\t"       \
        "s_waitcnt vmcnt(0)"                                                 \
        : [q0]"=&v"(P[0]),  [q1]"=&v"(P[1]),  [q2]"=&v"(P[2]),               \
          [q3]"=&v"(P[3]),  [q4]"=&v"(P[4]),  [q5]"=&v"(P[5]),               \
          [q6]"=&v"(P[6]),  [q7]"=&v"(P[7]),  [q8]"=&v"(P[8]),               \
          [q9]"=&v"(P[9]),  [qa]"=&v"(P[10]), [qb]"=&v"(P[11]),              \
          [qc]"=&v"(P[12]), [qd]"=&v"(P[13]), [qe]"=&v"(P[14]),              \
          [qf]"=&v"(P[15])                                                   \
        : [pb]"v"(PKB) : "memory")

__global__ __launch_bounds__(256, 1) void rnn_steps(
    const int*   __restrict__ x,          // [NSEQ][TSEQ]
    const float* __restrict__ e2,         // [VOCAB][HDIM]  (E + bh)
    const _Float16* __restrict__ whhT_hi, // [HDIM][HDIM] j-major
    const _Float16* __restrict__ whhT_lo,
    unsigned* __restrict__ hpk,           // [2][NSEQ][HDIM] packed h
    unsigned* __restrict__ claims,        // [8] for this chunk
    _Float16* __restrict__ z,             // chunk: [tc][NSEQ*HDIM]
    float* __restrict__ hlast_out,        // [NSEQ*HDIM]
    int t0, int t1)
{
    const int tid  = threadIdx.x;
    const int lane = tid & 63;
    const int w    = tid >> 6;         // wave 0..3 = k-quarter
    const int lq   = lane >> 4;        // k sub-chunk 0..3

    __shared__ _Float16 bls[2][32][2][64][8];  // 128 KB Whh^T frags hi/lo
    __shared__ f32x4    red[2][4][2][64];      //  16 KB partials, dbuf by parity
    __shared__ int      slot_s;
    __shared__ unsigned xcd_s;

    // ---- claim a worker slot on this physical XCD
    if (tid == 0) {
        unsigned xcd;
        asm volatile("s_getreg_b32 %0, hwreg(HW_REG_XCC_ID)" : "=s"(xcd));
        xcd &= 7;
        xcd_s  = xcd;
        slot_s = (int)atomicAdd(&claims[xcd], 1u);
    }
    __syncthreads();
    const int slot = slot_s;
    if (slot >= 32) return;            // surplus block
    const unsigned xcd = xcd_s;
    const int gbase = (int)xcd * 8;    // this XCD's 8 sequences
    const int j0c   = slot * 32;       // this WG's 32 columns

    // ---- one-time: stage B fragments (32 cols, hi+lo) into LDS
    for (int idx = tid; idx < 8192; idx += 256) {
        int l   = idx & 63;
        int ct_ = (idx >> 6) & 1;
        int m   = (idx >> 7) & 31;
        int pl_ = idx >> 12;
        int col = j0c + ct_ * 16 + (l & 15);
        int k   = m * 32 + (l >> 4) * 8;
        const _Float16* s = (pl_ ? whhT_lo : whhT_hi) + (size_t)col * HDIM + k;
        *(f16x8*)&bls[pl_][m][ct_][l][0] = *(const f16x8*)s;
    }
    __syncthreads();

    const int rowA = lane & 7;

    // epilogue role: one output value per thread
    const int erow = tid >> 5;         // 0..7
    const int ecol = tid & 31;         // 0..31
    const int gn   = gbase + erow;
    const int jcol = j0c + ecol;
    const int ctE  = ecol >> 4;
    const int laneE= ((erow >> 2) << 4) | (ecol & 15);
    const int rE   = erow & 3;

    int   tokv = x[(size_t)gn * TSEQ + t0];
    float ev   = e2[(size_t)tokv * HDIM + jcol];

    for (int t = t0; t < t1; ++t) {
        const int par = t & 1;
        // prefetch next step's token + E value (read-only, cached)
        int tn = (t + 1 < TSEQ) ? t + 1 : TSEQ - 1;
        int tok_n = x[(size_t)gn * TSEQ + tn];
        float e_n = e2[(size_t)tok_n * HDIM + jcol];

        // ---- self-certifying A fetch: retry burst until every dword's gen
        // bit (bit 16) equals gexp = (t>>1)&1.
        const unsigned* pkb = hpk + (size_t)(t & 1) * HPLANE
                            + (size_t)(gbase + rowA) * HDIM + w * 256 + lq * 8;
        const int gexp = (t >> 1) & 1;
        u32x4 P[16];
        int guard = 1 << 14;
        for (;;) {
            LOADPK(P, pkb);
            if (t == 0) break;  // h0 written by rnn_init (stream-ordered)
            unsigned acc;
            if (gexp) {         // expect bit16 == 1 in all dwords: AND-tree
                acc = 0xFFFFFFFFu;
                #pragma unroll
                for (int i = 0; i < 16; ++i)
                    acc &= P[i].x & P[i].y & P[i].z & P[i].w;
                if (__all((int)((acc >> 16) & 1u))) break;
            } else {            // expect bit16 == 0 in all dwords: OR-tree
                acc = 0u;
                #pragma unroll
                for (int i = 0; i < 16; ++i)
                    acc |= P[i].x | P[i].y | P[i].z | P[i].w;
                if (__all((int)(((acc >> 16) & 1u) == 0u))) break;
            }
            if (--guard <= 0) break;   // liveness hedge -> absmax fail
        }

        // ---- unpack + MFMA: both col-tiles, k-quarter w
        f32x4 a0c0 = {0.f,0.f,0.f,0.f}, a1c0 = {0.f,0.f,0.f,0.f};
        f32x4 a0c1 = {0.f,0.f,0.f,0.f}, a1c1 = {0.f,0.f,0.f,0.f};
        #pragma unroll
        for (int mi = 0; mi < 8; ++mi) {
            u32x4 A0 = P[2 * mi], A1 = P[2 * mi + 1];
            u32x4 hh = { __builtin_amdgcn_perm(A0.y, A0.x, 0x05040100u),
                         __builtin_amdgcn_perm(A0.w, A0.z, 0x05040100u),
                         __builtin_amdgcn_perm(A1.y, A1.x, 0x05040100u),
                         __builtin_amdgcn_perm(A1.w, A1.z, 0x05040100u) };
            u32x4 ll = { __builtin_amdgcn_perm(A0.y, A0.x, 0x07060302u),
                         __builtin_amdgcn_perm(A0.w, A0.z, 0x07060302u),
                         __builtin_amdgcn_perm(A1.y, A1.x, 0x07060302u),
                         __builtin_amdgcn_perm(A1.w, A1.z, 0x07060302u) };
            f16x8 ah = *(f16x8*)&hh;
            f16x8 al = *(f16x8*)&ll;
            const int m = w * 8 + mi;
            f16x8 b0h = *(const f16x8*)&bls[0][m][0][lane][0];
            f16x8 b0l = *(const f16x8*)&bls[1][m][0][lane][0];
            f16x8 b1h = *(const f16x8*)&bls[0][m][1][lane][0];
            f16x8 b1l = *(const f16x8*)&bls[1][m][1][lane][0];
            a0c0 = __builtin_amdgcn_mfma_f32_16x16x32_f16(ah, b0h, a0c0, 0, 0, 0);
            a1c0 = __builtin_amdgcn_mfma_f32_16x16x32_f16(al, b0h, a1c0, 0, 0, 0);
            a1c0 = __builtin_amdgcn_mfma_f32_16x16x32_f16(ah, b0l, a1c0, 0, 0, 0);
            a0c1 = __builtin_amdgcn_mfma_f32_16x16x32_f16(ah, b1h, a0c1, 0, 0, 0);
            a1c1 = __builtin_amdgcn_mfma_f32_16x16x32_f16(al, b1h, a1c1, 0, 0, 0);
            a1c1 = __builtin_amdgcn_mfma_f32_16x16x32_f16(ah, b1l, a1c1, 0, 0, 0);
        }
        f32x4 p0, p1;
        #pragma unroll
        for (int r = 0; r < 4; ++r) {
            p0[r] = a0c0[r] + a1c0[r] * LOINV;
            p1[r] = a0c1[r] + a1c1[r] * LOINV;
        }
        red[par][w][0][lane] = p0;
        red[par][w][1][lane] = p1;
        __syncthreads();   // the ONLY per-step barrier

        // ---- epilogue: thread -> (erow, ecol); sum 4 k-quarter partials
        float s = ((const float*)&red[par][0][ctE][laneE])[rE]
                + ((const float*)&red[par][1][ctE][laneE])[rE]
                + ((const float*)&red[par][2][ctE][laneE])[rE]
                + ((const float*)&red[par][3][ctE][laneE])[rE];
        float pre = s + ev;
        float hv  = tanhf(pre);
        _Float16 h16 = (_Float16)hv;
        _Float16 l16 = (_Float16)((hv - (float)h16) * LOSCALE);
        union { _Float16 f; unsigned short u; } uh{h16}, ul{l16};
        const unsigned gw = (unsigned)(((t + 1) >> 1) & 1);
        unsigned pk = (unsigned)uh.u
                    | ((((unsigned)ul.u & 0xFFFEu) | gw) << 16);

        {   // packed h store -> L3, fire-and-forget (data self-certifies)
            unsigned* pdst = hpk + (size_t)((t + 1) & 1) * HPLANE
                           + (size_t)gn * HDIM + jcol;
            asm volatile("global_store_dword %0, %1, off sc0 sc1"
                         :: "v"(pdst), "v"(pk) : "memory");
        }
        // z / hlast: off the critical path (cached)
        z[(size_t)(t - t0) * HPLANE + (size_t)gn * HDIM + jcol] = h16;
        if (t == TSEQ - 1) hlast_out[(size_t)gn * HDIM + jcol] = hv;
        tokv = tok_n; ev = e_n;
    }
}

// ---------------------------------------------------------------- output GEMM + softmax
__global__ __launch_bounds__(256, 1) void rnn_out(
    const _Float16* __restrict__ z,      // chunk: [tc][NSEQ*HDIM]
    const _Float16* __restrict__ woutT,  // [ODIM][HDIM]
    const float* __restrict__ bout,      // [ODIM]
    float* __restrict__ y,               // [NSEQ][TSEQ][ODIM]
    int t0, int tc)
{
    const int b = blockIdx.x;
    const int t_rel = b >> 2, ng = b & 3;
    const int t = t0 + t_rel;
    const int n0 = ng * 16;
    const int tid = threadIdx.x;
    const int lane = tid & 63, wv = tid >> 6;
    const int lr = lane & 15, lq = lane >> 4;

    __shared__ float lg[16][ODIM + 8];   // logits staging

    const _Float16* abase = z + (size_t)t_rel * (NSEQ * HDIM)
                              + (size_t)(n0 + lr) * HDIM + lq * 8;
    f16x8 af[32];
    #pragma unroll
    for (int m = 0; m < 32; ++m) af[m] = *(const f16x8*)(abase + m * 32);

    #pragma unroll
    for (int i = 0; i < 4; ++i) {
        int ot = (wv * 4 + i) * 16;
        const _Float16* bbase = woutT + (size_t)(ot + lr) * HDIM + lq * 8;
        f32x4 acc = {0.f, 0.f, 0.f, 0.f};
        #pragma unroll
        for (int m = 0; m < 32; ++m) {
            f16x8 bfr = *(const f16x8*)(bbase + m * 32);
            acc = __builtin_amdgcn_mfma_f32_16x16x32_f16(af[m], bfr, acc, 0, 0, 0);
        }
        #pragma unroll
        for (int r = 0; r < 4; ++r)
            lg[lq * 4 + r][ot + lr] = acc[r];
    }
    __syncthreads();

    for (int rr = 0; rr < 4; ++rr) {
        int row = wv * 4 + rr;
        int n = n0 + row;
        float v0 = lg[row][lane]       + bout[lane];
        float v1 = lg[row][64 + lane]  + bout[64 + lane];
        float v2 = lg[row][128 + lane] + bout[128 + lane];
        float v3 = lg[row][192 + lane] + bout[192 + lane];
        float mx = fmaxf(fmaxf(v0, v1), fmaxf(v2, v3));
        for (int s = 32; s > 0; s >>= 1) mx = fmaxf(mx, __shfl_xor(mx, s));
        float e0 = __expf(v0 - mx), e1 = __expf(v1 - mx);
        float e2v = __expf(v2 - mx), e3 = __expf(v3 - mx);
        float sm = e0 + e1 + e2v + e3;
        for (int s = 32; s > 0; s >>= 1) sm += __shfl_xor(sm, s);
        float inv = 1.f / sm;
        float* dst = y + ((size_t)n * TSEQ + t) * ODIM;
        dst[lane]       = e0 * inv;
        dst[64 + lane]  = e1 * inv;
        dst[128 + lane] = e2v * inv;
        dst[192 + lane] = e3 * inv;
    }
}

// ---------------------------------------------------------------- launch
extern "C" void kernel_launch(void* const* d_in, const int* in_sizes, int n_in,
                              void* d_out, int out_size, void* d_ws, size_t ws_size,
                              hipStream_t stream)
{
    const int*   x    = (const int*)  d_in[0];
    const float* E    = (const float*)d_in[1];
    const float* Whh  = (const float*)d_in[2];
    const float* bh   = (const float*)d_in[3];
    const float* Wout = (const float*)d_in[4];
    const float* bout = (const float*)d_in[5];

    float* y     = (float*)d_out;
    float* hlast = y + (size_t)NSEQ * TSEQ * ODIM;

    char* ws = (char*)d_ws;
    size_t off = 0;
    auto alloc = [&](size_t bytes) -> void* {
        void* p = ws + off;
        off = (off + bytes + 255) & ~(size_t)255;
        return p;
    };
    _Float16* whhT_hi = (_Float16*)alloc((size_t)HDIM * HDIM * 2);
    _Float16* whhT_lo = (_Float16*)alloc((size_t)HDIM * HDIM * 2);
    _Float16* woutT   = (_Float16*)alloc((size_t)ODIM * HDIM * 2);
    float*    e2      = (float*)   alloc((size_t)VOCABSZ * HDIM * 4);
    unsigned* hpk     = (unsigned*)alloc((size_t)2 * HPLANE * 4);
    unsigned* claims  = (unsigned*)alloc((size_t)64 * 8 * 4);
    _Float16* z       = (_Float16*)(ws + off);

    size_t zcap = (ws_size > off) ? (ws_size - off) : 0;
    int tc_max = (int)(zcap / ((size_t)NSEQ * HDIM * 2));
    if (tc_max > TSEQ) tc_max = TSEQ;
    if (tc_max < 1)    tc_max = 1;

    rnn_init<<<2048, 256, 0, stream>>>(Whh, Wout, E, bh, whhT_hi, whhT_lo,
                                       woutT, e2, hpk, claims);

    int chunk = 0;
    for (int t0 = 0; t0 < TSEQ; t0 += tc_max, ++chunk) {
        int tc = TSEQ - t0 < tc_max ? TSEQ - t0 : tc_max;
        rnn_steps<<<1024, 256, 0, stream>>>(x, e2, whhT_hi, whhT_lo, hpk,
                                            claims + (chunk & 63) * 8,
                                            z, hlast, t0, t0 + tc);
        rnn_out<<<tc * 4, 256, 0, stream>>>(z, woutT, bout, y, t0, tc);
    }
}